// Round 3
// baseline (11001.778 us; speedup 1.0000x reference)
//
#include <hip/hip_runtime.h>
#include <hip/hip_bf16.h>

// ---------------------------------------------------------------------------
// VGG16 perceptual+style inpainting loss. fp32 direct conv, fused pooling.
// Streams (gt, out, comp) processed sequentially to bound workspace usage:
//   NB=2 mode (both batch samples per chain)  needs ~233 MB of d_ws
//   NB=1 mode (one sample per chain)          needs ~117 MB of d_ws
// Selected at runtime from ws_size (constant per session -> capture-safe).
// Output: scalar float32 (reference computes in f32).
// ---------------------------------------------------------------------------

__device__ __forceinline__ float blk_sum256(float v, float* s4) {
#pragma unroll
  for (int o = 32; o > 0; o >>= 1) v += __shfl_down(v, o);
  int w = threadIdx.x >> 6;
  if ((threadIdx.x & 63) == 0) s4[w] = v;
  __syncthreads();
  float r = s4[0] + s4[1] + s4[2] + s4[3];
  __syncthreads();
  return r;
}

__global__ void init_slots(float* slots) {
  if (threadIdx.x < 8) slots[threadIdx.x] = 0.0f;
}

// l_hole / l_valid partial sums over the full [2,3,512,512] tensors.
__global__ __launch_bounds__(256) void l1_kernel(
    const float* __restrict__ igt, const float* __restrict__ iout,
    const float* __restrict__ mask, float* __restrict__ slots) {
  __shared__ float s4[4];
  int idx = blockIdx.x * 256 + threadIdx.x;  // < 1,572,864
  int pix = idx & 262143;                    // % (512*512)
  int n = idx / 786432;                      // batch sample 0..1
  float mk = mask[n * 262144 + pix];
  bool m = (mk != 0.0f);
  float d = fabsf(iout[idx] - igt[idx]);
  float r = blk_sum256(m ? 0.0f : d, s4);
  if (threadIdx.x == 0) atomicAdd(&slots[0], r);
  r = blk_sum256(m ? d : 0.0f, s4);
  if (threadIdx.x == 0) atomicAdd(&slots[1], r);
}

// Build x0 [NB,3,512,512] for stream sid (0=gt,1=out,2=comp), samples n0..n0+NB-1.
__global__ __launch_bounds__(256) void pack_kernel(
    const float* __restrict__ igt, const float* __restrict__ iout,
    const float* __restrict__ mask, float* __restrict__ x0, int sid, int n0,
    int NB) {
  int i = blockIdx.x * 256 + threadIdx.x;
  if (i >= NB * 786432) return;
  int nl = i / 786432;
  int rem = i - nl * 786432;
  int sample = n0 + nl;
  float v;
  if (sid == 0) {
    v = igt[sample * 786432 + rem];
  } else if (sid == 1) {
    v = iout[sample * 786432 + rem];
  } else {
    int pix = rem & 262143;
    float mk = mask[sample * 262144 + pix];
    v = (mk != 0.0f) ? igt[sample * 786432 + rem] : iout[sample * 786432 + rem];
  }
  x0[i] = v;
}

// Direct 3x3 SAME conv + bias + relu, optional fused 2x2 maxpool.
// Block: 256 thr = 32 (x) x 8 (row-quads); thread = 1 col x 4 rows x 16 cout.
// grid.z = n_images * (Cout/16).
template <bool POOL>
__global__ __launch_bounds__(256) void conv3x3_k(
    const float* __restrict__ in, const float* __restrict__ wgt,
    const float* __restrict__ bias, float* __restrict__ out,
    int Cin, int Cout, int H, int W) {
  constexpr int TCO = 16;
  constexpr int CIB = 4;
  __shared__ float s_in[CIB][34][34];
  __shared__ float s_w[CIB][9][TCO];

  const int tid = threadIdx.x;
  const int tx = tid & 31;
  const int tyq = tid >> 5;  // 0..7
  const int bx = blockIdx.x, by = blockIdx.y;
  const int cob = Cout / TCO;
  const int n = blockIdx.z / cob;
  const int co0 = (blockIdx.z % cob) * TCO;
  const int x0g = bx * 32 - 1;
  const int y0g = by * 32 - 1;

  float acc[4][TCO];
#pragma unroll
  for (int p = 0; p < 4; ++p)
#pragma unroll
    for (int t = 0; t < TCO; ++t) acc[p][t] = 0.0f;

  for (int cb = 0; cb < Cin; cb += CIB) {
    const int cnt = min(CIB, Cin - cb);
    const int tot = cnt * 1156;  // 34*34 per channel
    for (int e = tid; e < tot; e += 256) {
      int ci = e / 1156;
      int rem = e - ci * 1156;
      int r = rem / 34;
      int c = rem - r * 34;
      int gy = y0g + r, gx = x0g + c;
      float v = 0.0f;
      if (gy >= 0 && gy < H && gx >= 0 && gx < W)
        v = in[((long)(n * Cin + cb + ci) * H + gy) * W + gx];
      s_in[ci][r][c] = v;
    }
    const int wtot = cnt * 9 * TCO;
    for (int e = tid; e < wtot; e += 256) {
      int ci = e / (9 * TCO);
      int rem = e - ci * 9 * TCO;
      int k = rem / TCO;
      int t = rem - k * TCO;
      s_w[ci][k][t] = wgt[((co0 + t) * Cin + cb + ci) * 9 + k];
    }
    __syncthreads();

    for (int ci = 0; ci < cnt; ++ci) {
      float iv[6][3];
#pragma unroll
      for (int dr = 0; dr < 6; ++dr)
#pragma unroll
        for (int dc = 0; dc < 3; ++dc)
          iv[dr][dc] = s_in[ci][tyq * 4 + dr][tx + dc];
#pragma unroll
      for (int ky = 0; ky < 3; ++ky) {
#pragma unroll
        for (int kx = 0; kx < 3; ++kx) {
          const int kk = ky * 3 + kx;
          const float4 w0 = *(const float4*)&s_w[ci][kk][0];
          const float4 w1 = *(const float4*)&s_w[ci][kk][4];
          const float4 w2 = *(const float4*)&s_w[ci][kk][8];
          const float4 w3 = *(const float4*)&s_w[ci][kk][12];
          const float wv[16] = {w0.x, w0.y, w0.z, w0.w, w1.x, w1.y, w1.z, w1.w,
                                w2.x, w2.y, w2.z, w2.w, w3.x, w3.y, w3.z, w3.w};
#pragma unroll
          for (int p = 0; p < 4; ++p) {
            const float v = iv[p + ky][kx];
#pragma unroll
            for (int t = 0; t < TCO; ++t) acc[p][t] += v * wv[t];
          }
        }
      }
    }
    __syncthreads();
  }

  float bv[TCO];
#pragma unroll
  for (int t = 0; t < TCO; ++t) bv[t] = bias[co0 + t];

  if (!POOL) {
    const int xg = bx * 32 + tx;
#pragma unroll
    for (int t = 0; t < TCO; ++t)
#pragma unroll
      for (int p = 0; p < 4; ++p) {
        int yg = by * 32 + tyq * 4 + p;
        float v = fmaxf(acc[p][t] + bv[t], 0.0f);
        out[((long)(n * Cout + co0 + t) * H + yg) * W + xg] = v;
      }
  } else {
    const int Hp = H >> 1, Wp = W >> 1;
    const int xp = bx * 16 + (tx >> 1);
#pragma unroll
    for (int t = 0; t < TCO; ++t)
#pragma unroll
      for (int pp = 0; pp < 2; ++pp) {
        float v0 = fmaxf(acc[2 * pp][t] + bv[t], 0.0f);
        float v1 = fmaxf(acc[2 * pp + 1][t] + bv[t], 0.0f);
        float m = fmaxf(v0, v1);
        m = fmaxf(m, __shfl_xor(m, 1));
        if ((tx & 1) == 0) {
          int yp = by * 16 + tyq * 2 + pp;
          out[((long)(n * Cout + co0 + t) * Hp + yp) * Wp + xp] = m;
        }
      }
  }
}

// l_perc partial: sum |cur - gt| over M elements -> slots[2]
__global__ __launch_bounds__(256) void perc_kernel(
    const float* __restrict__ gt, const float* __restrict__ cur, int M,
    float* __restrict__ slots) {
  __shared__ float s4[4];
  float acc = 0.0f;
  for (int i = blockIdx.x * 256 + threadIdx.x; i < M; i += gridDim.x * 256)
    acc += fabsf(cur[i] - gt[i]);
  float r = blk_sum256(acc, s4);
  if (threadIdx.x == 0) atomicAdd(&slots[2], r);
}

// Style partial: per plane z (one (sample,channel)), WxW Gram of gt & cur,
// accumulate fscale * sum |Gcur - Ggt| over this block's 64x64 tile -> slots[3]
__global__ __launch_bounds__(256) void gram_kernel(
    const float* __restrict__ gt_p, const float* __restrict__ cur_p, int Hp,
    int Wp, float fscale, float* __restrict__ slots) {
  __shared__ float s_a[2][8][64];
  __shared__ float s_b[2][8][64];
  __shared__ float s4[4];
  const int tid = threadIdx.x;
  const int wi = tid & 15, vi = tid >> 4;
  const int wt = blockIdx.x * 64, vt = blockIdx.y * 64;
  const long plane = (long)Hp * Wp;
  const float* gB = gt_p + blockIdx.z * plane;
  const float* cB = cur_p + blockIdx.z * plane;

  float ag[4][4] = {{0}}, ac[4][4] = {{0}};
  for (int h0 = 0; h0 < Hp; h0 += 8) {
    for (int e = tid; e < 1024; e += 256) {
      int t = e >> 9;
      int rem = e & 511;
      int hh = rem >> 6;
      int col = rem & 63;
      const float* src = t ? cB : gB;
      s_a[t][hh][col] = src[(h0 + hh) * Wp + wt + col];
      s_b[t][hh][col] = src[(h0 + hh) * Wp + vt + col];
    }
    __syncthreads();
#pragma unroll
    for (int hh = 0; hh < 8; ++hh) {
      const float4 ga4 = *(const float4*)&s_a[0][hh][wi * 4];
      const float4 gb4 = *(const float4*)&s_b[0][hh][vi * 4];
      const float4 ca4 = *(const float4*)&s_a[1][hh][wi * 4];
      const float4 cb4 = *(const float4*)&s_b[1][hh][vi * 4];
      const float gaA[4] = {ga4.x, ga4.y, ga4.z, ga4.w};
      const float gbA[4] = {gb4.x, gb4.y, gb4.z, gb4.w};
      const float caA[4] = {ca4.x, ca4.y, ca4.z, ca4.w};
      const float cbA[4] = {cb4.x, cb4.y, cb4.z, cb4.w};
#pragma unroll
      for (int i = 0; i < 4; ++i)
#pragma unroll
        for (int j = 0; j < 4; ++j) {
          ag[i][j] += gaA[i] * gbA[j];
          ac[i][j] += caA[i] * cbA[j];
        }
    }
    __syncthreads();
  }
  float local = 0.0f;
#pragma unroll
  for (int i = 0; i < 4; ++i)
#pragma unroll
    for (int j = 0; j < 4; ++j) local += fabsf(ac[i][j] - ag[i][j]);
  float r = blk_sum256(local, s4);
  if (tid == 0) atomicAdd(&slots[3], r * fscale);
}

__global__ void combine_kernel(const float* __restrict__ slots,
                               float* __restrict__ out) {
  if (threadIdx.x == 0) {
    const float Nn = 1572864.0f;    // 3*512*512*2
    const float Nigt = 8388608.0f;  // 2*64*256*256 (faithful perc normalizer)
    out[0] = 2.0f * slots[0] / Nn + slots[1] / Nn + slots[2] / Nigt + slots[3];
  }
}

extern "C" void kernel_launch(void* const* d_in, const int* in_sizes, int n_in,
                              void* d_out, int out_size, void* d_ws,
                              size_t ws_size, hipStream_t stream) {
  (void)in_sizes; (void)n_in; (void)out_size;
  const float* igt = (const float*)d_in[0];
  const float* iout = (const float*)d_in[1];
  const float* mask = (const float*)d_in[2];
  const float* w[7];
  const float* b[7];
  for (int i = 0; i < 7; ++i) {
    w[i] = (const float*)d_in[3 + 2 * i];
    b[i] = (const float*)d_in[4 + 2 * i];
  }
  float* slots = (float*)d_ws;

  // Per-group float counts (NB = samples per chain):
  //   pg1 NB*4194304 | pg2 NB*2097152 | pg3 NB*1048576 | pc NB*4194304
  //   x0 NB*786432   | bufA NB*16777216  -> total NB*29,097,984 floats
  const size_t NEED2 = 256 + (size_t)2 * 29097984 * 4;  // ~233 MB
  const int NBsel = (ws_size >= NEED2) ? 2 : 1;

  const float fs1 = (float)(1.0 / (4194304.0 * 4096.0));
  const float fs2 = (float)(1.0 / (2097152.0 * 16384.0));
  const float fs3 = (float)(1.0 / (1048576.0 * 65536.0));

  init_slots<<<1, 64, 0, stream>>>(slots);
  l1_kernel<<<6144, 256, 0, stream>>>(igt, iout, mask, slots);

  for (int n0 = 0; n0 < 2; n0 += NBsel) {
    const int NB = NBsel;
    float* base = (float*)((char*)d_ws + 256);
    float* pg1 = base;
    float* pg2 = pg1 + (size_t)NB * 4194304;
    float* pg3 = pg2 + (size_t)NB * 2097152;
    float* pc = pg3 + (size_t)NB * 1048576;
    float* x0 = pc + (size_t)NB * 4194304;
    float* bufA = x0 + (size_t)NB * 786432;
    float* y6 = bufA + (size_t)NB * 4194304;  // after y5's extent

    // ---- gt chain: pools land in pg1/pg2/pg3 ----
    pack_kernel<<<NB * 3072, 256, 0, stream>>>(igt, iout, mask, x0, 0, n0, NB);
    conv3x3_k<false><<<dim3(16, 16, NB * 4), 256, 0, stream>>>(x0, w[0], b[0], bufA, 3, 64, 512, 512);
    conv3x3_k<true><<<dim3(16, 16, NB * 4), 256, 0, stream>>>(bufA, w[1], b[1], pg1, 64, 64, 512, 512);
    conv3x3_k<false><<<dim3(8, 8, NB * 8), 256, 0, stream>>>(pg1, w[2], b[2], bufA, 64, 128, 256, 256);
    conv3x3_k<true><<<dim3(8, 8, NB * 8), 256, 0, stream>>>(bufA, w[3], b[3], pg2, 128, 128, 256, 256);
    conv3x3_k<false><<<dim3(4, 4, NB * 16), 256, 0, stream>>>(pg2, w[4], b[4], bufA, 128, 256, 128, 128);
    conv3x3_k<false><<<dim3(4, 4, NB * 16), 256, 0, stream>>>(bufA, w[5], b[5], y6, 256, 256, 128, 128);
    conv3x3_k<true><<<dim3(4, 4, NB * 16), 256, 0, stream>>>(y6, w[6], b[6], pg3, 256, 256, 128, 128);

    // ---- out / comp chains: pools land in pc, compared against pg* ----
    for (int s = 1; s <= 2; ++s) {
      pack_kernel<<<NB * 3072, 256, 0, stream>>>(igt, iout, mask, x0, s, n0, NB);
      conv3x3_k<false><<<dim3(16, 16, NB * 4), 256, 0, stream>>>(x0, w[0], b[0], bufA, 3, 64, 512, 512);
      conv3x3_k<true><<<dim3(16, 16, NB * 4), 256, 0, stream>>>(bufA, w[1], b[1], pc, 64, 64, 512, 512);
      perc_kernel<<<1024, 256, 0, stream>>>(pg1, pc, NB * 4194304, slots);
      gram_kernel<<<dim3(4, 4, NB * 64), 256, 0, stream>>>(pg1, pc, 256, 256, fs1, slots);
      conv3x3_k<false><<<dim3(8, 8, NB * 8), 256, 0, stream>>>(pc, w[2], b[2], bufA, 64, 128, 256, 256);
      conv3x3_k<true><<<dim3(8, 8, NB * 8), 256, 0, stream>>>(bufA, w[3], b[3], pc, 128, 128, 256, 256);
      perc_kernel<<<1024, 256, 0, stream>>>(pg2, pc, NB * 2097152, slots);
      gram_kernel<<<dim3(2, 2, NB * 128), 256, 0, stream>>>(pg2, pc, 128, 128, fs2, slots);
      conv3x3_k<false><<<dim3(4, 4, NB * 16), 256, 0, stream>>>(pc, w[4], b[4], bufA, 128, 256, 128, 128);
      conv3x3_k<false><<<dim3(4, 4, NB * 16), 256, 0, stream>>>(bufA, w[5], b[5], y6, 256, 256, 128, 128);
      conv3x3_k<true><<<dim3(4, 4, NB * 16), 256, 0, stream>>>(y6, w[6], b[6], pc, 256, 256, 128, 128);
      perc_kernel<<<1024, 256, 0, stream>>>(pg3, pc, NB * 1048576, slots);
      gram_kernel<<<dim3(1, 1, NB * 256), 256, 0, stream>>>(pg3, pc, 64, 64, fs3, slots);
    }
  }

  combine_kernel<<<1, 64, 0, stream>>>(slots, (float*)d_out);
}

// Round 4
// 2133.327 us; speedup vs baseline: 5.1571x; 5.1571x over previous
//
#include <hip/hip_runtime.h>
#include <hip/hip_bf16.h>

// ---------------------------------------------------------------------------
// VGG16 perceptual+style inpainting loss.
// conv2..conv7 on bf16 MFMA (NHWC activations), conv1 fp32-direct -> NHWC bf16.
// Pool = standalone kernel emitting bf16 NHWC (conv chain) + fp32 planar
// (gram/perc path, unchanged from round 3). Gram/perc/l1 fp32, proven.
// Workspace: 3.3MB packed weights + NB*96.5MB (aliased), NB adaptive.
// ---------------------------------------------------------------------------

typedef __attribute__((ext_vector_type(8))) short bf16x8_t;
typedef __attribute__((ext_vector_type(4))) float f32x4_t;

__device__ __forceinline__ float blk_sum256(float v, float* s4) {
#pragma unroll
  for (int o = 32; o > 0; o >>= 1) v += __shfl_down(v, o);
  int w = threadIdx.x >> 6;
  if ((threadIdx.x & 63) == 0) s4[w] = v;
  __syncthreads();
  float r = s4[0] + s4[1] + s4[2] + s4[3];
  __syncthreads();
  return r;
}

__global__ void init_slots(float* slots) {
  if (threadIdx.x < 8) slots[threadIdx.x] = 0.0f;
}

// l_hole / l_valid partial sums over the full [2,3,512,512] tensors.
__global__ __launch_bounds__(256) void l1_kernel(
    const float* __restrict__ igt, const float* __restrict__ iout,
    const float* __restrict__ mask, float* __restrict__ slots) {
  __shared__ float s4[4];
  int idx = blockIdx.x * 256 + threadIdx.x;  // < 1,572,864
  int pix = idx & 262143;
  int n = idx / 786432;
  float mk = mask[n * 262144 + pix];
  bool m = (mk != 0.0f);
  float d = fabsf(iout[idx] - igt[idx]);
  float r = blk_sum256(m ? 0.0f : d, s4);
  if (threadIdx.x == 0) atomicAdd(&slots[0], r);
  r = blk_sum256(m ? d : 0.0f, s4);
  if (threadIdx.x == 0) atomicAdd(&slots[1], r);
}

// Build x0 [NB,3,512,512] fp32 NCHW for stream sid (0=gt,1=out,2=comp).
__global__ __launch_bounds__(256) void pack_kernel(
    const float* __restrict__ igt, const float* __restrict__ iout,
    const float* __restrict__ mask, float* __restrict__ x0, int sid, int n0,
    int NB) {
  int i = blockIdx.x * 256 + threadIdx.x;
  if (i >= NB * 786432) return;
  int nl = i / 786432;
  int rem = i - nl * 786432;
  int sample = n0 + nl;
  float v;
  if (sid == 0) {
    v = igt[sample * 786432 + rem];
  } else if (sid == 1) {
    v = iout[sample * 786432 + rem];
  } else {
    int pix = rem & 262143;
    float mk = mask[sample * 262144 + pix];
    v = (mk != 0.0f) ? igt[sample * 786432 + rem] : iout[sample * 786432 + rem];
  }
  x0[i] = v;
}

// Pack fp32 OIHW weights -> bf16 [tap][cout][cin] (cin contiguous).
__global__ __launch_bounds__(256) void pack_w(const float* __restrict__ w,
                                              __hip_bfloat16* __restrict__ wp,
                                              int Cin, int Cout) {
  int i = blockIdx.x * 256 + threadIdx.x;
  if (i >= Cout * Cin * 9) return;
  int o = i % 9;
  int rem = i / 9;
  int ci = rem % Cin;
  int co = rem / Cin;
  wp[((long)(o * Cout + co)) * Cin + ci] = __float2bfloat16(w[i]);
}

// conv1: 3->64 fp32 direct (NCHW fp32 in), bias+relu, bf16 NHWC out.
__global__ __launch_bounds__(256) void conv1_k(
    const float* __restrict__ in, const float* __restrict__ wgt,
    const float* __restrict__ bias, __hip_bfloat16* __restrict__ out,
    int H, int W) {
  constexpr int TCO = 16;
  constexpr int Cin = 3;
  __shared__ float s_in[Cin][34][34];
  __shared__ float s_w[Cin][9][TCO];
  const int tid = threadIdx.x;
  const int tx = tid & 31;
  const int tyq = tid >> 5;
  const int bx = blockIdx.x, by = blockIdx.y;
  const int n = blockIdx.z >> 2;
  const int co0 = (blockIdx.z & 3) * TCO;
  const int x0g = bx * 32 - 1;
  const int y0g = by * 32 - 1;

  float acc[4][TCO];
#pragma unroll
  for (int p = 0; p < 4; ++p)
#pragma unroll
    for (int t = 0; t < TCO; ++t) acc[p][t] = 0.0f;

  for (int e = tid; e < Cin * 1156; e += 256) {
    int ci = e / 1156;
    int rem = e - ci * 1156;
    int r = rem / 34;
    int c = rem - r * 34;
    int gy = y0g + r, gx = x0g + c;
    float v = 0.0f;
    if (gy >= 0 && gy < H && gx >= 0 && gx < W)
      v = in[((long)(n * Cin + ci) * H + gy) * W + gx];
    s_in[ci][r][c] = v;
  }
  for (int e = tid; e < Cin * 9 * TCO; e += 256) {
    int ci = e / (9 * TCO);
    int rem = e - ci * 9 * TCO;
    int k = rem / TCO;
    int t = rem - k * TCO;
    s_w[ci][k][t] = wgt[((co0 + t) * Cin + ci) * 9 + k];
  }
  __syncthreads();

  for (int ci = 0; ci < Cin; ++ci) {
    float iv[6][3];
#pragma unroll
    for (int dr = 0; dr < 6; ++dr)
#pragma unroll
      for (int dc = 0; dc < 3; ++dc)
        iv[dr][dc] = s_in[ci][tyq * 4 + dr][tx + dc];
#pragma unroll
    for (int ky = 0; ky < 3; ++ky)
#pragma unroll
      for (int kx = 0; kx < 3; ++kx) {
        const int kk = ky * 3 + kx;
        const float4 w0 = *(const float4*)&s_w[ci][kk][0];
        const float4 w1 = *(const float4*)&s_w[ci][kk][4];
        const float4 w2 = *(const float4*)&s_w[ci][kk][8];
        const float4 w3 = *(const float4*)&s_w[ci][kk][12];
        const float wv[16] = {w0.x, w0.y, w0.z, w0.w, w1.x, w1.y, w1.z, w1.w,
                              w2.x, w2.y, w2.z, w2.w, w3.x, w3.y, w3.z, w3.w};
#pragma unroll
        for (int p = 0; p < 4; ++p) {
          const float v = iv[p + ky][kx];
#pragma unroll
          for (int t = 0; t < TCO; ++t) acc[p][t] += v * wv[t];
        }
      }
  }

  float bv[TCO];
#pragma unroll
  for (int t = 0; t < TCO; ++t) bv[t] = bias[co0 + t];
  const int xg = bx * 32 + tx;
#pragma unroll
  for (int p = 0; p < 4; ++p) {
    int yg = by * 32 + tyq * 4 + p;
#pragma unroll
    for (int t = 0; t < TCO; ++t) {
      float v = fmaxf(acc[p][t] + bv[t], 0.0f);
      out[(((long)n * H + yg) * W + xg) * 64 + co0 + t] = __float2bfloat16(v);
    }
  }
}

// MFMA 3x3 SAME conv + bias + relu, bf16 NHWC in/out.
// Block: 256 thr = 4 waves; tile 256 px (2 rows x 128) x 64 couts.
// Wave (wy,wx): 128 px x 32 co; 8 m-tiles x 2 n-tiles of 16x16 MFMA.
// K-loop: ci-chunks of 32, 9 taps per chunk.
__global__ __launch_bounds__(256, 2) void conv_mfma(
    const __hip_bfloat16* __restrict__ act,
    const __hip_bfloat16* __restrict__ wp, const float* __restrict__ bias,
    __hip_bfloat16* __restrict__ out, int Cin, int Cout, int H, int W) {
  __shared__ __align__(16) short Ap[4][4][130][8];  // [kg][row][x][ci8]
  __shared__ __align__(16) short Bw[4][9][64][8];   // [kg][tap][co][ci8]
  const int tid = threadIdx.x;
  const int lane = tid & 63;
  const int wv = tid >> 6;
  const int wy = wv >> 1, wx = wv & 1;
  const int quad = lane >> 4, l15 = lane & 15;
  const int coB = Cout >> 6;
  const int n = blockIdx.z / coB;
  const int co0 = (blockIdx.z % coB) << 6;
  const int x0 = blockIdx.x << 7, y0 = blockIdx.y << 1;

  f32x4_t acc[8][2];
#pragma unroll
  for (int mt = 0; mt < 8; ++mt) {
    acc[mt][0] = (f32x4_t)0.0f;
    acc[mt][1] = (f32x4_t)0.0f;
  }

  for (int cb = 0; cb < Cin; cb += 32) {
    // stage input patch: rows y0-1..y0+2, x x0-1..x0+128, 32 ci
    for (int pos = tid; pos < 520; pos += 256) {
      int r = pos / 130, c = pos - r * 130;
      int gy = y0 - 1 + r, gx = x0 - 1 + c;
      uint4 v0 = make_uint4(0, 0, 0, 0), v1 = v0, v2 = v0, v3 = v0;
      if (gy >= 0 && gy < H && gx >= 0 && gx < W) {
        const uint4* src =
            (const uint4*)(act + (((long)n * H + gy) * W + gx) * Cin + cb);
        v0 = src[0]; v1 = src[1]; v2 = src[2]; v3 = src[3];
      }
      *(uint4*)&Ap[0][r][c][0] = v0;
      *(uint4*)&Ap[1][r][c][0] = v1;
      *(uint4*)&Ap[2][r][c][0] = v2;
      *(uint4*)&Ap[3][r][c][0] = v3;
    }
    // stage weights: 9 taps x 64 couts x 32 ci
    for (int pos = tid; pos < 576; pos += 256) {
      int o = pos / 64, co = pos - o * 64;
      const uint4* src =
          (const uint4*)(wp + ((long)(o * Cout + co0 + co)) * Cin + cb);
      *(uint4*)&Bw[0][o][co][0] = src[0];
      *(uint4*)&Bw[1][o][co][0] = src[1];
      *(uint4*)&Bw[2][o][co][0] = src[2];
      *(uint4*)&Bw[3][o][co][0] = src[3];
    }
    __syncthreads();

    for (int o = 0; o < 9; ++o) {
      const int dy = o / 3, dx = o % 3;
      bf16x8_t b0 = *(const bf16x8_t*)&Bw[quad][o][wx * 32 + l15][0];
      bf16x8_t b1 = *(const bf16x8_t*)&Bw[quad][o][wx * 32 + 16 + l15][0];
#pragma unroll
      for (int mt = 0; mt < 8; ++mt) {
        int p = wy * 128 + mt * 16 + l15;
        bf16x8_t a =
            *(const bf16x8_t*)&Ap[quad][(p >> 7) + dy][(p & 127) + dx][0];
        acc[mt][0] =
            __builtin_amdgcn_mfma_f32_16x16x32_bf16(a, b0, acc[mt][0], 0, 0, 0);
        acc[mt][1] =
            __builtin_amdgcn_mfma_f32_16x16x32_bf16(a, b1, acc[mt][1], 0, 0, 0);
      }
    }
    __syncthreads();
  }

  float bv0 = bias[co0 + wx * 32 + l15];
  float bv1 = bias[co0 + wx * 32 + 16 + l15];
#pragma unroll
  for (int mt = 0; mt < 8; ++mt)
#pragma unroll
    for (int nt = 0; nt < 2; ++nt) {
      float bb = nt ? bv1 : bv0;
      int col = co0 + wx * 32 + nt * 16 + l15;
#pragma unroll
      for (int reg = 0; reg < 4; ++reg) {
        int p = wy * 128 + mt * 16 + quad * 4 + reg;
        int y = y0 + (p >> 7), x = x0 + (p & 127);
        float v = fmaxf(acc[mt][nt][reg] + bb, 0.0f);
        out[(((long)n * H + y) * W + x) * Cout + col] = __float2bfloat16(v);
      }
    }
}

// 2x2 maxpool: bf16 NHWC in -> bf16 NHWC out + fp32 planar [nl][C][Ho][Wo].
// Block: 256 = 8 wo x 32 c. Grid: (Wo/8, Ho, NB*C/32).
__global__ __launch_bounds__(256) void pool_kernel(
    const __hip_bfloat16* __restrict__ in, __hip_bfloat16* __restrict__ out_n,
    float* __restrict__ out_p, int C, int H, int W) {
  const int Ho = H >> 1, Wo = W >> 1;
  const int cl = threadIdx.x & 31;
  const int wl = threadIdx.x >> 5;
  const int cg = C >> 5;
  const int nl = blockIdx.z / cg;
  const int c = (blockIdx.z % cg) * 32 + cl;
  const int wo = blockIdx.x * 8 + wl;
  const int ho = blockIdx.y;
  long base = (((long)nl * H + 2 * ho) * W + 2 * wo) * C + c;
  float a = __bfloat162float(in[base]);
  float b = __bfloat162float(in[base + C]);
  float d = __bfloat162float(in[base + (long)W * C]);
  float e = __bfloat162float(in[base + (long)W * C + C]);
  float m = fmaxf(fmaxf(a, b), fmaxf(d, e));
  out_n[(((long)nl * Ho + ho) * Wo + wo) * C + c] = __float2bfloat16(m);
  out_p[(((long)nl * C + c) * Ho + ho) * Wo + wo] = m;
}

// l_perc partial: sum |cur - gt| over M elements -> slots[2]
__global__ __launch_bounds__(256) void perc_kernel(
    const float* __restrict__ gt, const float* __restrict__ cur, int M,
    float* __restrict__ slots) {
  __shared__ float s4[4];
  float acc = 0.0f;
  for (int i = blockIdx.x * 256 + threadIdx.x; i < M; i += gridDim.x * 256)
    acc += fabsf(cur[i] - gt[i]);
  float r = blk_sum256(acc, s4);
  if (threadIdx.x == 0) atomicAdd(&slots[2], r);
}

// Style partial on fp32 planar planes (unchanged from round 3).
__global__ __launch_bounds__(256) void gram_kernel(
    const float* __restrict__ gt_p, const float* __restrict__ cur_p, int Hp,
    int Wp, float fscale, float* __restrict__ slots) {
  __shared__ float s_a[2][8][64];
  __shared__ float s_b[2][8][64];
  __shared__ float s4[4];
  const int tid = threadIdx.x;
  const int wi = tid & 15, vi = tid >> 4;
  const int wt = blockIdx.x * 64, vt = blockIdx.y * 64;
  const long plane = (long)Hp * Wp;
  const float* gB = gt_p + blockIdx.z * plane;
  const float* cB = cur_p + blockIdx.z * plane;

  float ag[4][4] = {{0}}, ac[4][4] = {{0}};
  for (int h0 = 0; h0 < Hp; h0 += 8) {
    for (int e = tid; e < 1024; e += 256) {
      int t = e >> 9;
      int rem = e & 511;
      int hh = rem >> 6;
      int col = rem & 63;
      const float* src = t ? cB : gB;
      s_a[t][hh][col] = src[(h0 + hh) * Wp + wt + col];
      s_b[t][hh][col] = src[(h0 + hh) * Wp + vt + col];
    }
    __syncthreads();
#pragma unroll
    for (int hh = 0; hh < 8; ++hh) {
      const float4 ga4 = *(const float4*)&s_a[0][hh][wi * 4];
      const float4 gb4 = *(const float4*)&s_b[0][hh][vi * 4];
      const float4 ca4 = *(const float4*)&s_a[1][hh][wi * 4];
      const float4 cb4 = *(const float4*)&s_b[1][hh][vi * 4];
      const float gaA[4] = {ga4.x, ga4.y, ga4.z, ga4.w};
      const float gbA[4] = {gb4.x, gb4.y, gb4.z, gb4.w};
      const float caA[4] = {ca4.x, ca4.y, ca4.z, ca4.w};
      const float cbA[4] = {cb4.x, cb4.y, cb4.z, cb4.w};
#pragma unroll
      for (int i = 0; i < 4; ++i)
#pragma unroll
        for (int j = 0; j < 4; ++j) {
          ag[i][j] += gaA[i] * gbA[j];
          ac[i][j] += caA[i] * cbA[j];
        }
    }
    __syncthreads();
  }
  float local = 0.0f;
#pragma unroll
  for (int i = 0; i < 4; ++i)
#pragma unroll
    for (int j = 0; j < 4; ++j) local += fabsf(ac[i][j] - ag[i][j]);
  float r = blk_sum256(local, s4);
  if (tid == 0) atomicAdd(&slots[3], r * fscale);
}

__global__ void combine_kernel(const float* __restrict__ slots,
                               float* __restrict__ out) {
  if (threadIdx.x == 0) {
    const float Nn = 1572864.0f;
    const float Nigt = 8388608.0f;
    out[0] = 2.0f * slots[0] / Nn + slots[1] / Nn + slots[2] / Nigt + slots[3];
  }
}

extern "C" void kernel_launch(void* const* d_in, const int* in_sizes, int n_in,
                              void* d_out, int out_size, void* d_ws,
                              size_t ws_size, hipStream_t stream) {
  (void)in_sizes; (void)n_in; (void)out_size;
  const float* igt = (const float*)d_in[0];
  const float* iout = (const float*)d_in[1];
  const float* mask = (const float*)d_in[2];
  const float* w[7];
  const float* b[7];
  for (int i = 0; i < 7; ++i) {
    w[i] = (const float*)d_in[3 + 2 * i];
    b[i] = (const float*)d_in[4 + 2 * i];
  }
  float* slots = (float*)d_ws;

  // Packed weight buffer (layers 1..6 of the conv stack), bf16.
  __hip_bfloat16* wpk = (__hip_bfloat16*)((char*)d_ws + 256);
  const long wpOff[6] = {0, 36864, 110592, 258048, 552960, 1142784};
  const int wpCin[6] = {64, 64, 128, 128, 256, 256};
  const int wpCout[6] = {64, 128, 128, 256, 256, 256};
  // bytes: 256 + 3,465,216 = 3,465,472 to first act buffer

  // Per-group need: bufA + bufB (2*NB*33,554,432) + pg1/2/3 (NB*29,360,128).
  const size_t NEED2 = 3465472ULL + 2ULL * 96468992ULL;  // 196,403,456
  const int NB = (ws_size >= NEED2) ? 2 : 1;

  char* base = (char*)d_ws + 3465472;
  __hip_bfloat16* bufA = (__hip_bfloat16*)base;
  __hip_bfloat16* bufB = (__hip_bfloat16*)(base + (size_t)NB * 33554432);
  float* pg1 = (float*)(base + (size_t)NB * 67108864);
  float* pg2 = pg1 + (size_t)NB * 4194304;
  float* pg3 = pg2 + (size_t)NB * 2097152;
  float* x0 = (float*)(base + (size_t)NB * 33554432 +
                       (size_t)NB * (33554432 - 3145728));  // bufB tail
  float* pcf1 = (float*)((char*)bufA + (size_t)NB * 8388608);
  float* pcf2 = (float*)((char*)bufB + (size_t)NB * 4194304);
  float* pcf3 = (float*)((char*)bufB + (size_t)NB * 2097152);

  const float fs1 = (float)(1.0 / (4194304.0 * 4096.0));
  const float fs2 = (float)(1.0 / (2097152.0 * 16384.0));
  const float fs3 = (float)(1.0 / (1048576.0 * 65536.0));

  init_slots<<<1, 64, 0, stream>>>(slots);
  l1_kernel<<<6144, 256, 0, stream>>>(igt, iout, mask, slots);
  for (int l = 0; l < 6; ++l) {
    int elems = wpCout[l] * wpCin[l] * 9;
    pack_w<<<(elems + 255) / 256, 256, 0, stream>>>(w[l + 1], wpk + wpOff[l],
                                                    wpCin[l], wpCout[l]);
  }

  for (int n0 = 0; n0 < 2; n0 += NB) {
    for (int s = 0; s < 3; ++s) {
      float* d1 = (s == 0) ? pg1 : pcf1;
      float* d2 = (s == 0) ? pg2 : pcf2;
      float* d3 = (s == 0) ? pg3 : pcf3;
      pack_kernel<<<NB * 3072, 256, 0, stream>>>(igt, iout, mask, x0, s, n0, NB);
      conv1_k<<<dim3(16, 16, NB * 4), 256, 0, stream>>>(x0, w[0], b[0], bufA, 512, 512);
      conv_mfma<<<dim3(4, 256, NB * 1), 256, 0, stream>>>(bufA, wpk + wpOff[0], b[1], bufB, 64, 64, 512, 512);
      pool_kernel<<<dim3(32, 256, NB * 2), 256, 0, stream>>>(bufB, bufA, d1, 64, 512, 512);
      if (s > 0) {
        perc_kernel<<<1024, 256, 0, stream>>>(pg1, d1, NB * 4194304, slots);
        gram_kernel<<<dim3(4, 4, NB * 64), 256, 0, stream>>>(pg1, d1, 256, 256, fs1, slots);
      }
      conv_mfma<<<dim3(2, 128, NB * 2), 256, 0, stream>>>(bufA, wpk + wpOff[1], b[2], bufB, 64, 128, 256, 256);
      conv_mfma<<<dim3(2, 128, NB * 2), 256, 0, stream>>>(bufB, wpk + wpOff[2], b[3], bufA, 128, 128, 256, 256);
      pool_kernel<<<dim3(16, 128, NB * 4), 256, 0, stream>>>(bufA, bufB, d2, 128, 256, 256);
      if (s > 0) {
        perc_kernel<<<1024, 256, 0, stream>>>(pg2, d2, NB * 2097152, slots);
        gram_kernel<<<dim3(2, 2, NB * 128), 256, 0, stream>>>(pg2, d2, 128, 128, fs2, slots);
      }
      conv_mfma<<<dim3(1, 64, NB * 4), 256, 0, stream>>>(bufB, wpk + wpOff[3], b[4], bufA, 128, 256, 128, 128);
      conv_mfma<<<dim3(1, 64, NB * 4), 256, 0, stream>>>(bufA, wpk + wpOff[4], b[5], bufB, 256, 256, 128, 128);
      conv_mfma<<<dim3(1, 64, NB * 4), 256, 0, stream>>>(bufB, wpk + wpOff[5], b[6], bufA, 256, 256, 128, 128);
      pool_kernel<<<dim3(8, 64, NB * 8), 256, 0, stream>>>(bufA, bufB, d3, 256, 128, 128);
      if (s > 0) {
        perc_kernel<<<1024, 256, 0, stream>>>(pg3, d3, NB * 1048576, slots);
        gram_kernel<<<dim3(1, 1, NB * 256), 256, 0, stream>>>(pg3, d3, 64, 64, fs3, slots);
      }
    }
  }

  combine_kernel<<<1, 64, 0, stream>>>(slots, (float*)d_out);
}

// Round 5
// 1626.987 us; speedup vs baseline: 6.7621x; 1.3112x over previous
//
#include <hip/hip_runtime.h>
#include <hip/hip_bf16.h>

// ---------------------------------------------------------------------------
// VGG16 perceptual+style inpainting loss.
// conv2..7: bf16 MFMA NHWC (unchanged from r4). conv1 fp32->NHWC bf16.
// Pools: bf16 NHWC (conv chain) + bf16 column-major planar [plane][x][y]
// (gram K-dim contiguous). Gram: bf16 MFMA, both tensors per wave.
// l1/perc: grid-stride, ~300 atomics (was ~18K serialized).
// Workspace: 3.3MB weights + NB*85MB, NB adaptive (NEED2 = 173.3MB).
// ---------------------------------------------------------------------------

typedef __attribute__((ext_vector_type(8))) short bf16x8_t;
typedef __attribute__((ext_vector_type(4))) float f32x4_t;

__device__ __forceinline__ float b2f(__hip_bfloat16 v) {
  return __bfloat162float(v);
}

__device__ __forceinline__ float blk_sum256(float v, float* s4) {
#pragma unroll
  for (int o = 32; o > 0; o >>= 1) v += __shfl_down(v, o);
  int w = threadIdx.x >> 6;
  if ((threadIdx.x & 63) == 0) s4[w] = v;
  __syncthreads();
  float r = s4[0] + s4[1] + s4[2] + s4[3];
  __syncthreads();
  return r;
}

__global__ void init_slots(float* slots) {
  if (threadIdx.x < 8) slots[threadIdx.x] = 0.0f;
}

// l_hole / l_valid: grid-stride (few blocks -> few atomics).
__global__ __launch_bounds__(256) void l1_kernel(
    const float* __restrict__ igt, const float* __restrict__ iout,
    const float* __restrict__ mask, float* __restrict__ slots) {
  __shared__ float s4[4];
  float ah = 0.0f, av = 0.0f;
  for (int idx = blockIdx.x * 256 + threadIdx.x; idx < 1572864;
       idx += gridDim.x * 256) {
    int pix = idx & 262143;
    int n = idx / 786432;
    float mk = mask[n * 262144 + pix];
    bool m = (mk != 0.0f);
    float d = fabsf(iout[idx] - igt[idx]);
    if (m) av += d; else ah += d;
  }
  float r = blk_sum256(ah, s4);
  if (threadIdx.x == 0) atomicAdd(&slots[0], r);
  r = blk_sum256(av, s4);
  if (threadIdx.x == 0) atomicAdd(&slots[1], r);
}

// Build x0 [NB,3,512,512] fp32 NCHW for stream sid (0=gt,1=out,2=comp).
__global__ __launch_bounds__(256) void pack_kernel(
    const float* __restrict__ igt, const float* __restrict__ iout,
    const float* __restrict__ mask, float* __restrict__ x0, int sid, int n0,
    int NB) {
  int i = blockIdx.x * 256 + threadIdx.x;
  if (i >= NB * 786432) return;
  int nl = i / 786432;
  int rem = i - nl * 786432;
  int sample = n0 + nl;
  float v;
  if (sid == 0) {
    v = igt[sample * 786432 + rem];
  } else if (sid == 1) {
    v = iout[sample * 786432 + rem];
  } else {
    int pix = rem & 262143;
    float mk = mask[sample * 262144 + pix];
    v = (mk != 0.0f) ? igt[sample * 786432 + rem] : iout[sample * 786432 + rem];
  }
  x0[i] = v;
}

// Pack fp32 OIHW weights -> bf16 [tap][cout][cin].
__global__ __launch_bounds__(256) void pack_w(const float* __restrict__ w,
                                              __hip_bfloat16* __restrict__ wp,
                                              int Cin, int Cout) {
  int i = blockIdx.x * 256 + threadIdx.x;
  if (i >= Cout * Cin * 9) return;
  int o = i % 9;
  int rem = i / 9;
  int ci = rem % Cin;
  int co = rem / Cin;
  wp[((long)(o * Cout + co)) * Cin + ci] = __float2bfloat16(w[i]);
}

// conv1: 3->64 fp32 direct, bias+relu, bf16 NHWC out. (unchanged, r4-proven)
__global__ __launch_bounds__(256) void conv1_k(
    const float* __restrict__ in, const float* __restrict__ wgt,
    const float* __restrict__ bias, __hip_bfloat16* __restrict__ out,
    int H, int W) {
  constexpr int TCO = 16;
  constexpr int Cin = 3;
  __shared__ float s_in[Cin][34][34];
  __shared__ float s_w[Cin][9][TCO];
  const int tid = threadIdx.x;
  const int tx = tid & 31;
  const int tyq = tid >> 5;
  const int bx = blockIdx.x, by = blockIdx.y;
  const int n = blockIdx.z >> 2;
  const int co0 = (blockIdx.z & 3) * TCO;
  const int x0g = bx * 32 - 1;
  const int y0g = by * 32 - 1;

  float acc[4][TCO];
#pragma unroll
  for (int p = 0; p < 4; ++p)
#pragma unroll
    for (int t = 0; t < TCO; ++t) acc[p][t] = 0.0f;

  for (int e = tid; e < Cin * 1156; e += 256) {
    int ci = e / 1156;
    int rem = e - ci * 1156;
    int r = rem / 34;
    int c = rem - r * 34;
    int gy = y0g + r, gx = x0g + c;
    float v = 0.0f;
    if (gy >= 0 && gy < H && gx >= 0 && gx < W)
      v = in[((long)(n * Cin + ci) * H + gy) * W + gx];
    s_in[ci][r][c] = v;
  }
  for (int e = tid; e < Cin * 9 * TCO; e += 256) {
    int ci = e / (9 * TCO);
    int rem = e - ci * 9 * TCO;
    int k = rem / TCO;
    int t = rem - k * TCO;
    s_w[ci][k][t] = wgt[((co0 + t) * Cin + ci) * 9 + k];
  }
  __syncthreads();

  for (int ci = 0; ci < Cin; ++ci) {
    float iv[6][3];
#pragma unroll
    for (int dr = 0; dr < 6; ++dr)
#pragma unroll
      for (int dc = 0; dc < 3; ++dc)
        iv[dr][dc] = s_in[ci][tyq * 4 + dr][tx + dc];
#pragma unroll
    for (int ky = 0; ky < 3; ++ky)
#pragma unroll
      for (int kx = 0; kx < 3; ++kx) {
        const int kk = ky * 3 + kx;
        const float4 w0 = *(const float4*)&s_w[ci][kk][0];
        const float4 w1 = *(const float4*)&s_w[ci][kk][4];
        const float4 w2 = *(const float4*)&s_w[ci][kk][8];
        const float4 w3 = *(const float4*)&s_w[ci][kk][12];
        const float wv[16] = {w0.x, w0.y, w0.z, w0.w, w1.x, w1.y, w1.z, w1.w,
                              w2.x, w2.y, w2.z, w2.w, w3.x, w3.y, w3.z, w3.w};
#pragma unroll
        for (int p = 0; p < 4; ++p) {
          const float v = iv[p + ky][kx];
#pragma unroll
          for (int t = 0; t < TCO; ++t) acc[p][t] += v * wv[t];
        }
      }
  }

  float bv[TCO];
#pragma unroll
  for (int t = 0; t < TCO; ++t) bv[t] = bias[co0 + t];
  const int xg = bx * 32 + tx;
#pragma unroll
  for (int p = 0; p < 4; ++p) {
    int yg = by * 32 + tyq * 4 + p;
#pragma unroll
    for (int t = 0; t < TCO; ++t) {
      float v = fmaxf(acc[p][t] + bv[t], 0.0f);
      out[(((long)n * H + yg) * W + xg) * 64 + co0 + t] = __float2bfloat16(v);
    }
  }
}

// MFMA 3x3 SAME conv + bias + relu, bf16 NHWC. (unchanged, r4-proven)
__global__ __launch_bounds__(256, 2) void conv_mfma(
    const __hip_bfloat16* __restrict__ act,
    const __hip_bfloat16* __restrict__ wp, const float* __restrict__ bias,
    __hip_bfloat16* __restrict__ out, int Cin, int Cout, int H, int W) {
  __shared__ __align__(16) short Ap[4][4][130][8];
  __shared__ __align__(16) short Bw[4][9][64][8];
  const int tid = threadIdx.x;
  const int lane = tid & 63;
  const int wv = tid >> 6;
  const int wy = wv >> 1, wx = wv & 1;
  const int quad = lane >> 4, l15 = lane & 15;
  const int coB = Cout >> 6;
  const int n = blockIdx.z / coB;
  const int co0 = (blockIdx.z % coB) << 6;
  const int x0 = blockIdx.x << 7, y0 = blockIdx.y << 1;

  f32x4_t acc[8][2];
#pragma unroll
  for (int mt = 0; mt < 8; ++mt) {
    acc[mt][0] = (f32x4_t)0.0f;
    acc[mt][1] = (f32x4_t)0.0f;
  }

  for (int cb = 0; cb < Cin; cb += 32) {
    for (int pos = tid; pos < 520; pos += 256) {
      int r = pos / 130, c = pos - r * 130;
      int gy = y0 - 1 + r, gx = x0 - 1 + c;
      uint4 v0 = make_uint4(0, 0, 0, 0), v1 = v0, v2 = v0, v3 = v0;
      if (gy >= 0 && gy < H && gx >= 0 && gx < W) {
        const uint4* src =
            (const uint4*)(act + (((long)n * H + gy) * W + gx) * Cin + cb);
        v0 = src[0]; v1 = src[1]; v2 = src[2]; v3 = src[3];
      }
      *(uint4*)&Ap[0][r][c][0] = v0;
      *(uint4*)&Ap[1][r][c][0] = v1;
      *(uint4*)&Ap[2][r][c][0] = v2;
      *(uint4*)&Ap[3][r][c][0] = v3;
    }
    for (int pos = tid; pos < 576; pos += 256) {
      int o = pos / 64, co = pos - o * 64;
      const uint4* src =
          (const uint4*)(wp + ((long)(o * Cout + co0 + co)) * Cin + cb);
      *(uint4*)&Bw[0][o][co][0] = src[0];
      *(uint4*)&Bw[1][o][co][0] = src[1];
      *(uint4*)&Bw[2][o][co][0] = src[2];
      *(uint4*)&Bw[3][o][co][0] = src[3];
    }
    __syncthreads();

    for (int o = 0; o < 9; ++o) {
      const int dy = o / 3, dx = o % 3;
      bf16x8_t b0 = *(const bf16x8_t*)&Bw[quad][o][wx * 32 + l15][0];
      bf16x8_t b1 = *(const bf16x8_t*)&Bw[quad][o][wx * 32 + 16 + l15][0];
#pragma unroll
      for (int mt = 0; mt < 8; ++mt) {
        int p = wy * 128 + mt * 16 + l15;
        bf16x8_t a =
            *(const bf16x8_t*)&Ap[quad][(p >> 7) + dy][(p & 127) + dx][0];
        acc[mt][0] =
            __builtin_amdgcn_mfma_f32_16x16x32_bf16(a, b0, acc[mt][0], 0, 0, 0);
        acc[mt][1] =
            __builtin_amdgcn_mfma_f32_16x16x32_bf16(a, b1, acc[mt][1], 0, 0, 0);
      }
    }
    __syncthreads();
  }

  float bv0 = bias[co0 + wx * 32 + l15];
  float bv1 = bias[co0 + wx * 32 + 16 + l15];
#pragma unroll
  for (int mt = 0; mt < 8; ++mt)
#pragma unroll
    for (int nt = 0; nt < 2; ++nt) {
      float bb = nt ? bv1 : bv0;
      int col = co0 + wx * 32 + nt * 16 + l15;
#pragma unroll
      for (int reg = 0; reg < 4; ++reg) {
        int p = wy * 128 + mt * 16 + quad * 4 + reg;
        int y = y0 + (p >> 7), x = x0 + (p & 127);
        float v = fmaxf(acc[mt][nt][reg] + bb, 0.0f);
        out[(((long)n * H + y) * W + x) * Cout + col] = __float2bfloat16(v);
      }
    }
}

// 2x2 maxpool: bf16 NHWC in -> bf16 NHWC out + bf16 col-major planar
// out_pT[plane][x][y], plane = nl*C+c. Block 256 = 32c x 8wo; thread: 8 ho.
__global__ __launch_bounds__(256) void pool_k(
    const __hip_bfloat16* __restrict__ in, __hip_bfloat16* __restrict__ out_n,
    __hip_bfloat16* __restrict__ out_pT, int C, int H, int W) {
  const int Ho = H >> 1, Wo = W >> 1;
  const int cl = threadIdx.x & 31;
  const int wl = threadIdx.x >> 5;
  const int cg = C >> 5;
  const int nl = blockIdx.z / cg;
  const int c = (blockIdx.z % cg) * 32 + cl;
  const int wo = blockIdx.x * 8 + wl;
  const int ho0 = blockIdx.y * 8;
  __align__(16) __hip_bfloat16 res[8];
#pragma unroll
  for (int i = 0; i < 8; ++i) {
    int ho = ho0 + i;
    long base = (((long)nl * H + 2 * ho) * W + 2 * wo) * C + c;
    float a = b2f(in[base]);
    float b = b2f(in[base + C]);
    float d = b2f(in[base + (long)W * C]);
    float e = b2f(in[base + (long)W * C + C]);
    float m = fmaxf(fmaxf(a, b), fmaxf(d, e));
    __hip_bfloat16 r = __float2bfloat16(m);
    res[i] = r;
    out_n[(((long)nl * Ho + ho) * Wo + wo) * C + c] = r;
  }
  *(uint4*)&out_pT[((long)(nl * C + c) * Wo + wo) * Ho + ho0] =
      *(const uint4*)res;
}

// l_perc partial: sum |cur - gt| over 8*M8 bf16 elements -> slots[2]
__global__ __launch_bounds__(256) void perc_kernel(
    const __hip_bfloat16* __restrict__ gt, const __hip_bfloat16* __restrict__ cur,
    int M8, float* __restrict__ slots) {
  __shared__ float s4[4];
  const uint4* g4 = (const uint4*)gt;
  const uint4* c4 = (const uint4*)cur;
  float acc = 0.0f;
  for (int i = blockIdx.x * 256 + threadIdx.x; i < M8; i += gridDim.x * 256) {
    uint4 g = g4[i], c = c4[i];
    const unsigned* gu = (const unsigned*)&g;
    const unsigned* cu = (const unsigned*)&c;
#pragma unroll
    for (int k = 0; k < 4; ++k) {
      float g0 = __uint_as_float(gu[k] << 16);
      float g1 = __uint_as_float(gu[k] & 0xffff0000u);
      float c0 = __uint_as_float(cu[k] << 16);
      float c1 = __uint_as_float(cu[k] & 0xffff0000u);
      acc += fabsf(c0 - g0) + fabsf(c1 - g1);
    }
  }
  float r = blk_sum256(acc, s4);
  if (threadIdx.x == 0) atomicAdd(&slots[2], r);
}

// Style partial via bf16 MFMA. Inputs are col-major planar bf16 [plane][x][y]
// (K dim = y contiguous). Block: BM x 64 G-tile, both tensors; 4 waves split
// rows (BM/4 each). Grid: (Wp/64, Wp/BM, planes).
template <int BM>
__global__ __launch_bounds__(256) void gram_mfma(
    const __hip_bfloat16* __restrict__ gt_p,
    const __hip_bfloat16* __restrict__ cur_p, int Wp, int Hp, float fscale,
    float* __restrict__ slots) {
  constexpr int COLS = BM + 64;       // w-side + v-side strips
  constexpr int WR = BM / 4;          // rows per wave
  constexpr int MT = WR / 16;         // m-tiles per wave
  __shared__ __align__(16) short S[2 * COLS * 40];  // [t][col][40], 32 k used
  __shared__ float s4[4];
  const int tid = threadIdx.x;
  const int lane = tid & 63;
  const int wvi = tid >> 6;
  const int quad = lane >> 4, l15 = lane & 15;
  const int vt = blockIdx.x * 64;
  const int wt = blockIdx.y * BM;
  const long plane = (long)blockIdx.z * Wp * Hp;
  const __hip_bfloat16* bases[2] = {gt_p + plane, cur_p + plane};

  f32x4_t acc[2][MT][4];
#pragma unroll
  for (int t = 0; t < 2; ++t)
#pragma unroll
    for (int mt = 0; mt < MT; ++mt)
#pragma unroll
      for (int nt = 0; nt < 4; ++nt) acc[t][mt][nt] = (f32x4_t)0.0f;

  const int nchunk = 2 * COLS * 4;  // 16B chunks per round
  for (int h0 = 0; h0 < Hp; h0 += 32) {
    for (int e = tid; e < nchunk; e += 256) {
      int chunk = e & 3;
      int colt = e >> 2;
      int t = colt / COLS;
      int col = colt - t * COLS;
      int sc = (col < BM) ? (wt + col) : (vt + col - BM);
      uint4 v = *(const uint4*)(bases[t] + (long)sc * Hp + h0 + chunk * 8);
      *(uint4*)&S[(t * COLS + col) * 40 + chunk * 8] = v;
    }
    __syncthreads();
#pragma unroll
    for (int t = 0; t < 2; ++t) {
      bf16x8_t bf[4];
#pragma unroll
      for (int nt = 0; nt < 4; ++nt)
        bf[nt] = *(const bf16x8_t*)&S[(t * COLS + BM + nt * 16 + l15) * 40 +
                                      quad * 8];
#pragma unroll
      for (int mt = 0; mt < MT; ++mt) {
        bf16x8_t a = *(const bf16x8_t*)&S[(t * COLS + wvi * WR + mt * 16 + l15) *
                                              40 + quad * 8];
#pragma unroll
        for (int nt = 0; nt < 4; ++nt)
          acc[t][mt][nt] = __builtin_amdgcn_mfma_f32_16x16x32_bf16(
              a, bf[nt], acc[t][mt][nt], 0, 0, 0);
      }
    }
    __syncthreads();
  }

  float local = 0.0f;
#pragma unroll
  for (int mt = 0; mt < MT; ++mt)
#pragma unroll
    for (int nt = 0; nt < 4; ++nt)
#pragma unroll
      for (int reg = 0; reg < 4; ++reg)
        local += fabsf(acc[1][mt][nt][reg] - acc[0][mt][nt][reg]);
  float r = blk_sum256(local, s4);
  if (tid == 0) atomicAdd(&slots[3], r * fscale);
}

__global__ void combine_kernel(const float* __restrict__ slots,
                               float* __restrict__ out) {
  if (threadIdx.x == 0) {
    const float Nn = 1572864.0f;
    const float Nigt = 8388608.0f;
    out[0] = 2.0f * slots[0] / Nn + slots[1] / Nn + slots[2] / Nigt + slots[3];
  }
}

extern "C" void kernel_launch(void* const* d_in, const int* in_sizes, int n_in,
                              void* d_out, int out_size, void* d_ws,
                              size_t ws_size, hipStream_t stream) {
  (void)in_sizes; (void)n_in; (void)out_size;
  const float* igt = (const float*)d_in[0];
  const float* iout = (const float*)d_in[1];
  const float* mask = (const float*)d_in[2];
  const float* w[7];
  const float* b[7];
  for (int i = 0; i < 7; ++i) {
    w[i] = (const float*)d_in[3 + 2 * i];
    b[i] = (const float*)d_in[4 + 2 * i];
  }
  float* slots = (float*)d_ws;

  __hip_bfloat16* wpk = (__hip_bfloat16*)((char*)d_ws + 256);
  const long wpOff[6] = {0, 36864, 110592, 258048, 552960, 1142784};
  const int wpCin[6] = {64, 64, 128, 128, 256, 256};
  const int wpCout[6] = {64, 128, 128, 256, 256, 256};
  // weights end at byte 3,465,472

  const size_t NEED2 = 173334784ULL;
  const int NB = (ws_size >= NEED2) ? 2 : 1;

  char* base = (char*)d_ws + 3465472;
  __hip_bfloat16* bufA = (__hip_bfloat16*)base;
  __hip_bfloat16* bufB = (__hip_bfloat16*)(base + (size_t)NB * 33554432);
  __hip_bfloat16* pg1 = (__hip_bfloat16*)(base + (size_t)NB * 67108864);
  __hip_bfloat16* pg2 = pg1 + (size_t)NB * 4194304;
  __hip_bfloat16* pg3 = pg2 + (size_t)NB * 2097152;
  float* x0 = (float*)(base + (size_t)NB * 81788928);
  // cur pools live in bufA's tail (dead zones; see live-range comments):
  __hip_bfloat16* pc1 = bufA + (size_t)NB * 8388608;   // [16.8, 33.6) MB*NB
  __hip_bfloat16* pc2 = bufA + (size_t)NB * 12582912;  // [25.2, 33.6)
  __hip_bfloat16* pc3 = bufA + (size_t)NB * 14680064;  // [29.4, 33.6)

  const float fs1 = (float)(1.0 / (4194304.0 * 4096.0));
  const float fs2 = (float)(1.0 / (2097152.0 * 16384.0));
  const float fs3 = (float)(1.0 / (1048576.0 * 65536.0));

  init_slots<<<1, 64, 0, stream>>>(slots);
  l1_kernel<<<304, 256, 0, stream>>>(igt, iout, mask, slots);
  for (int l = 0; l < 6; ++l) {
    int elems = wpCout[l] * wpCin[l] * 9;
    pack_w<<<(elems + 255) / 256, 256, 0, stream>>>(w[l + 1], wpk + wpOff[l],
                                                    wpCin[l], wpCout[l]);
  }

  for (int n0 = 0; n0 < 2; n0 += NB) {
    for (int s = 0; s < 3; ++s) {
      __hip_bfloat16* d1 = (s == 0) ? pg1 : pc1;
      __hip_bfloat16* d2 = (s == 0) ? pg2 : pc2;
      __hip_bfloat16* d3 = (s == 0) ? pg3 : pc3;
      pack_kernel<<<NB * 3072, 256, 0, stream>>>(igt, iout, mask, x0, s, n0, NB);
      conv1_k<<<dim3(16, 16, NB * 4), 256, 0, stream>>>(x0, w[0], b[0], bufA, 512, 512);
      conv_mfma<<<dim3(4, 256, NB), 256, 0, stream>>>(bufA, wpk + wpOff[0], b[1], bufB, 64, 64, 512, 512);
      pool_k<<<dim3(32, 32, NB * 2), 256, 0, stream>>>(bufB, bufA, d1, 64, 512, 512);
      if (s > 0) {
        perc_kernel<<<304, 256, 0, stream>>>(pg1, pc1, NB * 524288, slots);
        gram_mfma<128><<<dim3(4, 2, NB * 64), 256, 0, stream>>>(pg1, pc1, 256, 256, fs1, slots);
      }
      conv_mfma<<<dim3(2, 128, NB * 2), 256, 0, stream>>>(bufA, wpk + wpOff[1], b[2], bufB, 64, 128, 256, 256);
      conv_mfma<<<dim3(2, 128, NB * 2), 256, 0, stream>>>(bufB, wpk + wpOff[2], b[3], bufA, 128, 128, 256, 256);
      pool_k<<<dim3(16, 16, NB * 4), 256, 0, stream>>>(bufA, bufB, d2, 128, 256, 256);
      if (s > 0) {
        perc_kernel<<<304, 256, 0, stream>>>(pg2, pc2, NB * 262144, slots);
        gram_mfma<128><<<dim3(2, 1, NB * 128), 256, 0, stream>>>(pg2, pc2, 128, 128, fs2, slots);
      }
      conv_mfma<<<dim3(1, 64, NB * 4), 256, 0, stream>>>(bufB, wpk + wpOff[3], b[4], bufA, 128, 256, 128, 128);
      conv_mfma<<<dim3(1, 64, NB * 4), 256, 0, stream>>>(bufA, wpk + wpOff[4], b[5], bufB, 256, 256, 128, 128);
      conv_mfma<<<dim3(1, 64, NB * 4), 256, 0, stream>>>(bufB, wpk + wpOff[5], b[6], bufA, 256, 256, 128, 128);
      pool_k<<<dim3(8, 8, NB * 8), 256, 0, stream>>>(bufA, bufB, d3, 256, 128, 128);
      if (s > 0) {
        perc_kernel<<<304, 256, 0, stream>>>(pg3, pc3, NB * 131072, slots);
        gram_mfma<64><<<dim3(1, 1, NB * 256), 256, 0, stream>>>(pg3, pc3, 64, 64, fs3, slots);
      }
    }
  }

  combine_kernel<<<1, 64, 0, stream>>>(slots, (float*)d_out);
}

// Round 6
// 1590.543 us; speedup vs baseline: 6.9170x; 1.0229x over previous
//
#include <hip/hip_runtime.h>
#include <hip/hip_bf16.h>

// ---------------------------------------------------------------------------
// VGG16 perceptual+style inpainting loss.
// conv2..7: bf16 MFMA NHWC, v2 tile (wave = 1 row x 128px x 64co, m8 x n4,
// conflict-free LDS; LDS/MFMA balanced). conv1 fp32->NHWC bf16.
// Pools: bf16 NHWC + bf16 col-major planar. Gram: bf16 MFMA (r5-proven).
// Workspace: 3.3MB weights + NB*85MB, NB adaptive.
// ---------------------------------------------------------------------------

typedef __attribute__((ext_vector_type(8))) short bf16x8_t;
typedef __attribute__((ext_vector_type(4))) float f32x4_t;

__device__ __forceinline__ float b2f(__hip_bfloat16 v) {
  return __bfloat162float(v);
}

__device__ __forceinline__ float blk_sum256(float v, float* s4) {
#pragma unroll
  for (int o = 32; o > 0; o >>= 1) v += __shfl_down(v, o);
  int w = threadIdx.x >> 6;
  if ((threadIdx.x & 63) == 0) s4[w] = v;
  __syncthreads();
  float r = s4[0] + s4[1] + s4[2] + s4[3];
  __syncthreads();
  return r;
}

__global__ void init_slots(float* slots) {
  if (threadIdx.x < 8) slots[threadIdx.x] = 0.0f;
}

// l_hole / l_valid: grid-stride.
__global__ __launch_bounds__(256) void l1_kernel(
    const float* __restrict__ igt, const float* __restrict__ iout,
    const float* __restrict__ mask, float* __restrict__ slots) {
  __shared__ float s4[4];
  float ah = 0.0f, av = 0.0f;
  for (int idx = blockIdx.x * 256 + threadIdx.x; idx < 1572864;
       idx += gridDim.x * 256) {
    int pix = idx & 262143;
    int n = idx / 786432;
    float mk = mask[n * 262144 + pix];
    bool m = (mk != 0.0f);
    float d = fabsf(iout[idx] - igt[idx]);
    if (m) av += d; else ah += d;
  }
  float r = blk_sum256(ah, s4);
  if (threadIdx.x == 0) atomicAdd(&slots[0], r);
  r = blk_sum256(av, s4);
  if (threadIdx.x == 0) atomicAdd(&slots[1], r);
}

// Build x0 [NB,3,512,512] fp32 NCHW for stream sid (0=gt,1=out,2=comp).
__global__ __launch_bounds__(256) void pack_kernel(
    const float* __restrict__ igt, const float* __restrict__ iout,
    const float* __restrict__ mask, float* __restrict__ x0, int sid, int n0,
    int NB) {
  int i = blockIdx.x * 256 + threadIdx.x;
  if (i >= NB * 786432) return;
  int nl = i / 786432;
  int rem = i - nl * 786432;
  int sample = n0 + nl;
  float v;
  if (sid == 0) {
    v = igt[sample * 786432 + rem];
  } else if (sid == 1) {
    v = iout[sample * 786432 + rem];
  } else {
    int pix = rem & 262143;
    float mk = mask[sample * 262144 + pix];
    v = (mk != 0.0f) ? igt[sample * 786432 + rem] : iout[sample * 786432 + rem];
  }
  x0[i] = v;
}

// Pack fp32 OIHW weights -> bf16 [tap][cout][cin].
__global__ __launch_bounds__(256) void pack_w(const float* __restrict__ w,
                                              __hip_bfloat16* __restrict__ wp,
                                              int Cin, int Cout) {
  int i = blockIdx.x * 256 + threadIdx.x;
  if (i >= Cout * Cin * 9) return;
  int o = i % 9;
  int rem = i / 9;
  int ci = rem % Cin;
  int co = rem / Cin;
  wp[((long)(o * Cout + co)) * Cin + ci] = __float2bfloat16(w[i]);
}

// conv1: 3->64 fp32 direct, bias+relu, bf16 NHWC out. (r4-proven)
__global__ __launch_bounds__(256) void conv1_k(
    const float* __restrict__ in, const float* __restrict__ wgt,
    const float* __restrict__ bias, __hip_bfloat16* __restrict__ out,
    int H, int W) {
  constexpr int TCO = 16;
  constexpr int Cin = 3;
  __shared__ float s_in[Cin][34][34];
  __shared__ float s_w[Cin][9][TCO];
  const int tid = threadIdx.x;
  const int tx = tid & 31;
  const int tyq = tid >> 5;
  const int bx = blockIdx.x, by = blockIdx.y;
  const int n = blockIdx.z >> 2;
  const int co0 = (blockIdx.z & 3) * TCO;
  const int x0g = bx * 32 - 1;
  const int y0g = by * 32 - 1;

  float acc[4][TCO];
#pragma unroll
  for (int p = 0; p < 4; ++p)
#pragma unroll
    for (int t = 0; t < TCO; ++t) acc[p][t] = 0.0f;

  for (int e = tid; e < Cin * 1156; e += 256) {
    int ci = e / 1156;
    int rem = e - ci * 1156;
    int r = rem / 34;
    int c = rem - r * 34;
    int gy = y0g + r, gx = x0g + c;
    float v = 0.0f;
    if (gy >= 0 && gy < H && gx >= 0 && gx < W)
      v = in[((long)(n * Cin + ci) * H + gy) * W + gx];
    s_in[ci][r][c] = v;
  }
  for (int e = tid; e < Cin * 9 * TCO; e += 256) {
    int ci = e / (9 * TCO);
    int rem = e - ci * 9 * TCO;
    int k = rem / TCO;
    int t = rem - k * TCO;
    s_w[ci][k][t] = wgt[((co0 + t) * Cin + ci) * 9 + k];
  }
  __syncthreads();

  for (int ci = 0; ci < Cin; ++ci) {
    float iv[6][3];
#pragma unroll
    for (int dr = 0; dr < 6; ++dr)
#pragma unroll
      for (int dc = 0; dc < 3; ++dc)
        iv[dr][dc] = s_in[ci][tyq * 4 + dr][tx + dc];
#pragma unroll
    for (int ky = 0; ky < 3; ++ky)
#pragma unroll
      for (int kx = 0; kx < 3; ++kx) {
        const int kk = ky * 3 + kx;
        const float4 w0 = *(const float4*)&s_w[ci][kk][0];
        const float4 w1 = *(const float4*)&s_w[ci][kk][4];
        const float4 w2 = *(const float4*)&s_w[ci][kk][8];
        const float4 w3 = *(const float4*)&s_w[ci][kk][12];
        const float wv[16] = {w0.x, w0.y, w0.z, w0.w, w1.x, w1.y, w1.z, w1.w,
                              w2.x, w2.y, w2.z, w2.w, w3.x, w3.y, w3.z, w3.w};
#pragma unroll
        for (int p = 0; p < 4; ++p) {
          const float v = iv[p + ky][kx];
#pragma unroll
          for (int t = 0; t < TCO; ++t) acc[p][t] += v * wv[t];
        }
      }
  }

  float bv[TCO];
#pragma unroll
  for (int t = 0; t < TCO; ++t) bv[t] = bias[co0 + t];
  const int xg = bx * 32 + tx;
#pragma unroll
  for (int p = 0; p < 4; ++p) {
    int yg = by * 32 + tyq * 4 + p;
#pragma unroll
    for (int t = 0; t < TCO; ++t) {
      float v = fmaxf(acc[p][t] + bv[t], 0.0f);
      out[(((long)n * H + yg) * W + xg) * 64 + co0 + t] = __float2bfloat16(v);
    }
  }
}

// ---------------------------------------------------------------------------
// conv_v2: MFMA 3x3 SAME conv + bias + relu, bf16 NHWC.
// Wave = 1 row x 128 px x 64 co (m8 x n4 of 16x16x32) -> 12 LDS reads per
// 32 MFMA (384 B/MFMA ~ balanced vs 4.85cyc MFMA). LDS layout: channels
// innermost (32/pixel, 64B) -> every inner b128 read is a contiguous 1KB
// per wave instruction: conflict-free.
// RB rows/block, COT couts/block, NW waves/block.
//   conv2:   <8, 64,8> 512thr  grid(W/128, H/8, NB)
//   conv3/4: <4,128,8> 512thr  grid(W/128, H/4, NB*(Cout/128))
//   conv5-7: <4, 64,4> 256thr  grid(W/128, H/4, NB*(Cout/64))
// ---------------------------------------------------------------------------
template <int RB, int COT, int NW>
__global__ __launch_bounds__(NW * 64, (NW == 8) ? 2 : 1) void conv_v2(
    const __hip_bfloat16* __restrict__ act,
    const __hip_bfloat16* __restrict__ wp, const float* __restrict__ bias,
    __hip_bfloat16* __restrict__ out, int Cin, int Cout, int H, int W) {
  constexpr int NT = NW * 64;
  __shared__ __align__(16) short ApS[(RB + 2) * 130 * 32];
  __shared__ __align__(16) short BwS[9 * COT * 32];
  const int tid = threadIdx.x;
  const int lane = tid & 63;
  const int wv = tid >> 6;
  const int quad = lane >> 4, l15 = lane & 15;
  const int wx = (COT == 128) ? (wv & 1) : 0;
  const int row = (COT == 128) ? (wv >> 1) : wv;
  const int coB = Cout / COT;
  const int n = blockIdx.z / coB;
  const int co0 = (blockIdx.z % coB) * COT;
  const int x0 = blockIdx.x << 7;
  const int y0 = blockIdx.y * RB;

  f32x4_t acc[8][4];
#pragma unroll
  for (int mt = 0; mt < 8; ++mt)
#pragma unroll
    for (int nt = 0; nt < 4; ++nt) acc[mt][nt] = (f32x4_t)0.0f;

  for (int cb = 0; cb < Cin; cb += 32) {
    // stage A: (RB+2) x 130 pixels x 32 ch; 16B (8ch) per thread-entry.
    for (int e = tid; e < (RB + 2) * 130 * 4; e += NT) {
      int q = e & 3, pos = e >> 2;
      int r = pos / 130, c = pos - r * 130;
      int gy = y0 - 1 + r, gx = x0 - 1 + c;
      uint4 v = make_uint4(0, 0, 0, 0);
      if (gy >= 0 && gy < H && gx >= 0 && gx < W)
        v = *(const uint4*)(act + (((long)n * H + gy) * W + gx) * Cin + cb +
                            q * 8);
      *(uint4*)&ApS[pos * 32 + q * 8] = v;
    }
    // stage B: 9 taps x COT couts x 32 ch.
    for (int e = tid; e < 9 * COT * 4; e += NT) {
      int q = e & 3, idx = e >> 2;
      int o = idx / COT, co = idx - o * COT;
      *(uint4*)&BwS[idx * 32 + q * 8] =
          *(const uint4*)(wp + ((long)(o * Cout + co0 + co)) * Cin + cb + q * 8);
    }
    __syncthreads();

#pragma unroll
    for (int o = 0; o < 9; ++o) {
      const int dy = o / 3, dx = o % 3;
      bf16x8_t bf[4];
#pragma unroll
      for (int nt = 0; nt < 4; ++nt)
        bf[nt] = *(const bf16x8_t*)&BwS[(o * COT + wx * 64 + nt * 16 + l15) *
                                            32 + quad * 8];
#pragma unroll
      for (int mt = 0; mt < 8; ++mt) {
        const bf16x8_t a =
            *(const bf16x8_t*)&ApS[((row + dy) * 130 + mt * 16 + l15 + dx) *
                                       32 + quad * 8];
#pragma unroll
        for (int nt = 0; nt < 4; ++nt)
          acc[mt][nt] = __builtin_amdgcn_mfma_f32_16x16x32_bf16(
              a, bf[nt], acc[mt][nt], 0, 0, 0);
      }
    }
    __syncthreads();
  }

  float bv[4];
#pragma unroll
  for (int nt = 0; nt < 4; ++nt) bv[nt] = bias[co0 + wx * 64 + nt * 16 + l15];
  const int y = y0 + row;
#pragma unroll
  for (int mt = 0; mt < 8; ++mt)
#pragma unroll
    for (int nt = 0; nt < 4; ++nt) {
      const int col = co0 + wx * 64 + nt * 16 + l15;
#pragma unroll
      for (int reg = 0; reg < 4; ++reg) {
        int px = mt * 16 + quad * 4 + reg;
        float v = fmaxf(acc[mt][nt][reg] + bv[nt], 0.0f);
        out[(((long)n * H + y) * W + x0 + px) * Cout + col] =
            __float2bfloat16(v);
      }
    }
}

// 2x2 maxpool: bf16 NHWC in -> bf16 NHWC out + bf16 col-major planar
// out_pT[plane][x][y]. Block 256 = 32c x 8wo; thread: 8 ho. (r5-proven)
__global__ __launch_bounds__(256) void pool_k(
    const __hip_bfloat16* __restrict__ in, __hip_bfloat16* __restrict__ out_n,
    __hip_bfloat16* __restrict__ out_pT, int C, int H, int W) {
  const int Ho = H >> 1, Wo = W >> 1;
  const int cl = threadIdx.x & 31;
  const int wl = threadIdx.x >> 5;
  const int cg = C >> 5;
  const int nl = blockIdx.z / cg;
  const int c = (blockIdx.z % cg) * 32 + cl;
  const int wo = blockIdx.x * 8 + wl;
  const int ho0 = blockIdx.y * 8;
  __align__(16) __hip_bfloat16 res[8];
#pragma unroll
  for (int i = 0; i < 8; ++i) {
    int ho = ho0 + i;
    long base = (((long)nl * H + 2 * ho) * W + 2 * wo) * C + c;
    float a = b2f(in[base]);
    float b = b2f(in[base + C]);
    float d = b2f(in[base + (long)W * C]);
    float e = b2f(in[base + (long)W * C + C]);
    float m = fmaxf(fmaxf(a, b), fmaxf(d, e));
    __hip_bfloat16 r = __float2bfloat16(m);
    res[i] = r;
    out_n[(((long)nl * Ho + ho) * Wo + wo) * C + c] = r;
  }
  *(uint4*)&out_pT[((long)(nl * C + c) * Wo + wo) * Ho + ho0] =
      *(const uint4*)res;
}

// l_perc partial: sum |cur - gt| over 8*M8 bf16 elements -> slots[2]
__global__ __launch_bounds__(256) void perc_kernel(
    const __hip_bfloat16* __restrict__ gt, const __hip_bfloat16* __restrict__ cur,
    int M8, float* __restrict__ slots) {
  __shared__ float s4[4];
  const uint4* g4 = (const uint4*)gt;
  const uint4* c4 = (const uint4*)cur;
  float acc = 0.0f;
  for (int i = blockIdx.x * 256 + threadIdx.x; i < M8; i += gridDim.x * 256) {
    uint4 g = g4[i], c = c4[i];
    const unsigned* gu = (const unsigned*)&g;
    const unsigned* cu = (const unsigned*)&c;
#pragma unroll
    for (int k = 0; k < 4; ++k) {
      float g0 = __uint_as_float(gu[k] << 16);
      float g1 = __uint_as_float(gu[k] & 0xffff0000u);
      float c0 = __uint_as_float(cu[k] << 16);
      float c1 = __uint_as_float(cu[k] & 0xffff0000u);
      acc += fabsf(c0 - g0) + fabsf(c1 - g1);
    }
  }
  float r = blk_sum256(acc, s4);
  if (threadIdx.x == 0) atomicAdd(&slots[2], r);
}

// Style partial via bf16 MFMA (r5-proven). Inputs col-major planar bf16.
template <int BM>
__global__ __launch_bounds__(256) void gram_mfma(
    const __hip_bfloat16* __restrict__ gt_p,
    const __hip_bfloat16* __restrict__ cur_p, int Wp, int Hp, float fscale,
    float* __restrict__ slots) {
  constexpr int COLS = BM + 64;
  constexpr int WR = BM / 4;
  constexpr int MT = WR / 16;
  __shared__ __align__(16) short S[2 * COLS * 40];
  __shared__ float s4[4];
  const int tid = threadIdx.x;
  const int lane = tid & 63;
  const int wvi = tid >> 6;
  const int quad = lane >> 4, l15 = lane & 15;
  const int vt = blockIdx.x * 64;
  const int wt = blockIdx.y * BM;
  const long plane = (long)blockIdx.z * Wp * Hp;
  const __hip_bfloat16* bases[2] = {gt_p + plane, cur_p + plane};

  f32x4_t acc[2][MT][4];
#pragma unroll
  for (int t = 0; t < 2; ++t)
#pragma unroll
    for (int mt = 0; mt < MT; ++mt)
#pragma unroll
      for (int nt = 0; nt < 4; ++nt) acc[t][mt][nt] = (f32x4_t)0.0f;

  const int nchunk = 2 * COLS * 4;
  for (int h0 = 0; h0 < Hp; h0 += 32) {
    for (int e = tid; e < nchunk; e += 256) {
      int chunk = e & 3;
      int colt = e >> 2;
      int t = colt / COLS;
      int col = colt - t * COLS;
      int sc = (col < BM) ? (wt + col) : (vt + col - BM);
      uint4 v = *(const uint4*)(bases[t] + (long)sc * Hp + h0 + chunk * 8);
      *(uint4*)&S[(t * COLS + col) * 40 + chunk * 8] = v;
    }
    __syncthreads();
#pragma unroll
    for (int t = 0; t < 2; ++t) {
      bf16x8_t bf[4];
#pragma unroll
      for (int nt = 0; nt < 4; ++nt)
        bf[nt] = *(const bf16x8_t*)&S[(t * COLS + BM + nt * 16 + l15) * 40 +
                                      quad * 8];
#pragma unroll
      for (int mt = 0; mt < MT; ++mt) {
        bf16x8_t a = *(const bf16x8_t*)&S[(t * COLS + wvi * WR + mt * 16 + l15) *
                                              40 + quad * 8];
#pragma unroll
        for (int nt = 0; nt < 4; ++nt)
          acc[t][mt][nt] = __builtin_amdgcn_mfma_f32_16x16x32_bf16(
              a, bf[nt], acc[t][mt][nt], 0, 0, 0);
      }
    }
    __syncthreads();
  }

  float local = 0.0f;
#pragma unroll
  for (int mt = 0; mt < MT; ++mt)
#pragma unroll
    for (int nt = 0; nt < 4; ++nt)
#pragma unroll
      for (int reg = 0; reg < 4; ++reg)
        local += fabsf(acc[1][mt][nt][reg] - acc[0][mt][nt][reg]);
  float r = blk_sum256(local, s4);
  if (tid == 0) atomicAdd(&slots[3], r * fscale);
}

__global__ void combine_kernel(const float* __restrict__ slots,
                               float* __restrict__ out) {
  if (threadIdx.x == 0) {
    const float Nn = 1572864.0f;
    const float Nigt = 8388608.0f;
    out[0] = 2.0f * slots[0] / Nn + slots[1] / Nn + slots[2] / Nigt + slots[3];
  }
}

extern "C" void kernel_launch(void* const* d_in, const int* in_sizes, int n_in,
                              void* d_out, int out_size, void* d_ws,
                              size_t ws_size, hipStream_t stream) {
  (void)in_sizes; (void)n_in; (void)out_size;
  const float* igt = (const float*)d_in[0];
  const float* iout = (const float*)d_in[1];
  const float* mask = (const float*)d_in[2];
  const float* w[7];
  const float* b[7];
  for (int i = 0; i < 7; ++i) {
    w[i] = (const float*)d_in[3 + 2 * i];
    b[i] = (const float*)d_in[4 + 2 * i];
  }
  float* slots = (float*)d_ws;

  __hip_bfloat16* wpk = (__hip_bfloat16*)((char*)d_ws + 256);
  const long wpOff[6] = {0, 36864, 110592, 258048, 552960, 1142784};
  const int wpCin[6] = {64, 64, 128, 128, 256, 256};
  const int wpCout[6] = {64, 128, 128, 256, 256, 256};
  // weights end at byte 3,465,472

  const size_t NEED2 = 173334784ULL;
  const int NB = (ws_size >= NEED2) ? 2 : 1;

  char* base = (char*)d_ws + 3465472;
  __hip_bfloat16* bufA = (__hip_bfloat16*)base;
  __hip_bfloat16* bufB = (__hip_bfloat16*)(base + (size_t)NB * 33554432);
  __hip_bfloat16* pg1 = (__hip_bfloat16*)(base + (size_t)NB * 67108864);
  __hip_bfloat16* pg2 = pg1 + (size_t)NB * 4194304;
  __hip_bfloat16* pg3 = pg2 + (size_t)NB * 2097152;
  float* x0 = (float*)(base + (size_t)NB * 81788928);
  // cur pools in bufA's dead tail zones (byte ranges verified non-overlapping
  // with every concurrent reader/writer):
  __hip_bfloat16* pc1 = bufA + (size_t)NB * 8388608;
  __hip_bfloat16* pc2 = bufA + (size_t)NB * 12582912;
  __hip_bfloat16* pc3 = bufA + (size_t)NB * 14680064;

  const float fs1 = (float)(1.0 / (4194304.0 * 4096.0));
  const float fs2 = (float)(1.0 / (2097152.0 * 16384.0));
  const float fs3 = (float)(1.0 / (1048576.0 * 65536.0));

  init_slots<<<1, 64, 0, stream>>>(slots);
  l1_kernel<<<304, 256, 0, stream>>>(igt, iout, mask, slots);
  for (int l = 0; l < 6; ++l) {
    int elems = wpCout[l] * wpCin[l] * 9;
    pack_w<<<(elems + 255) / 256, 256, 0, stream>>>(w[l + 1], wpk + wpOff[l],
                                                    wpCin[l], wpCout[l]);
  }

  for (int n0 = 0; n0 < 2; n0 += NB) {
    for (int s = 0; s < 3; ++s) {
      __hip_bfloat16* d1 = (s == 0) ? pg1 : pc1;
      __hip_bfloat16* d2 = (s == 0) ? pg2 : pc2;
      __hip_bfloat16* d3 = (s == 0) ? pg3 : pc3;
      pack_kernel<<<NB * 3072, 256, 0, stream>>>(igt, iout, mask, x0, s, n0, NB);
      conv1_k<<<dim3(16, 16, NB * 4), 256, 0, stream>>>(x0, w[0], b[0], bufA, 512, 512);
      conv_v2<8, 64, 8><<<dim3(4, 64, NB), 512, 0, stream>>>(
          bufA, wpk + wpOff[0], b[1], bufB, 64, 64, 512, 512);
      pool_k<<<dim3(32, 32, NB * 2), 256, 0, stream>>>(bufB, bufA, d1, 64, 512, 512);
      if (s > 0) {
        perc_kernel<<<304, 256, 0, stream>>>(pg1, pc1, NB * 524288, slots);
        gram_mfma<128><<<dim3(4, 2, NB * 64), 256, 0, stream>>>(pg1, pc1, 256, 256, fs1, slots);
      }
      conv_v2<4, 128, 8><<<dim3(2, 64, NB), 512, 0, stream>>>(
          bufA, wpk + wpOff[1], b[2], bufB, 64, 128, 256, 256);
      conv_v2<4, 128, 8><<<dim3(2, 64, NB), 512, 0, stream>>>(
          bufB, wpk + wpOff[2], b[3], bufA, 128, 128, 256, 256);
      pool_k<<<dim3(16, 16, NB * 4), 256, 0, stream>>>(bufA, bufB, d2, 128, 256, 256);
      if (s > 0) {
        perc_kernel<<<304, 256, 0, stream>>>(pg2, pc2, NB * 262144, slots);
        gram_mfma<128><<<dim3(2, 1, NB * 128), 256, 0, stream>>>(pg2, pc2, 128, 128, fs2, slots);
      }
      conv_v2<4, 64, 4><<<dim3(1, 32, NB * 4), 256, 0, stream>>>(
          bufB, wpk + wpOff[3], b[4], bufA, 128, 256, 128, 128);
      conv_v2<4, 64, 4><<<dim3(1, 32, NB * 4), 256, 0, stream>>>(
          bufA, wpk + wpOff[4], b[5], bufB, 256, 256, 128, 128);
      conv_v2<4, 64, 4><<<dim3(1, 32, NB * 4), 256, 0, stream>>>(
          bufB, wpk + wpOff[5], b[6], bufA, 256, 256, 128, 128);
      pool_k<<<dim3(8, 8, NB * 8), 256, 0, stream>>>(bufA, bufB, d3, 256, 128, 128);
      if (s > 0) {
        perc_kernel<<<304, 256, 0, stream>>>(pg3, pc3, NB * 131072, slots);
        gram_mfma<64><<<dim3(1, 1, NB * 256), 256, 0, stream>>>(pg3, pc3, 64, 64, fs3, slots);
      }
    }
  }

  combine_kernel<<<1, 64, 0, stream>>>(slots, (float*)d_out);
}

// Round 7
// 1469.848 us; speedup vs baseline: 7.4850x; 1.0821x over previous
//
#include <hip/hip_runtime.h>
#include <hip/hip_bf16.h>

// ---------------------------------------------------------------------------
// VGG16 perceptual+style inpainting loss.
// conv2..7: bf16 MFMA NHWC, v3: B-weights direct from global (L2-resident),
// LDS holds A-tile only (~42-50KB -> 3 blocks/CU). conv3..7 batched over all
// 3 streams (3NB images) for grid occupancy. conv4/conv7 fuse 2x2 maxpool
// in-register. conv1 fp32-direct. Gram/perc/l1 as r5/r6 (proven).
// Workspace tiers: NB=2 needs 211.1MB, NB=1 needs 107.3MB (< proven 116.4MB).
// ---------------------------------------------------------------------------

typedef __attribute__((ext_vector_type(8))) short bf16x8_t;
typedef __attribute__((ext_vector_type(4))) float f32x4_t;

__device__ __forceinline__ float b2f(__hip_bfloat16 v) {
  return __bfloat162float(v);
}

__device__ __forceinline__ float blk_sum256(float v, float* s4) {
#pragma unroll
  for (int o = 32; o > 0; o >>= 1) v += __shfl_down(v, o);
  int w = threadIdx.x >> 6;
  if ((threadIdx.x & 63) == 0) s4[w] = v;
  __syncthreads();
  float r = s4[0] + s4[1] + s4[2] + s4[3];
  __syncthreads();
  return r;
}

__global__ void init_slots(float* slots) {
  if (threadIdx.x < 8) slots[threadIdx.x] = 0.0f;
}

__global__ __launch_bounds__(256) void l1_kernel(
    const float* __restrict__ igt, const float* __restrict__ iout,
    const float* __restrict__ mask, float* __restrict__ slots) {
  __shared__ float s4[4];
  float ah = 0.0f, av = 0.0f;
  for (int idx = blockIdx.x * 256 + threadIdx.x; idx < 1572864;
       idx += gridDim.x * 256) {
    int pix = idx & 262143;
    int n = idx / 786432;
    float mk = mask[n * 262144 + pix];
    bool m = (mk != 0.0f);
    float d = fabsf(iout[idx] - igt[idx]);
    if (m) av += d; else ah += d;
  }
  float r = blk_sum256(ah, s4);
  if (threadIdx.x == 0) atomicAdd(&slots[0], r);
  r = blk_sum256(av, s4);
  if (threadIdx.x == 0) atomicAdd(&slots[1], r);
}

__global__ __launch_bounds__(256) void pack_kernel(
    const float* __restrict__ igt, const float* __restrict__ iout,
    const float* __restrict__ mask, float* __restrict__ x0, int sid, int n0,
    int NB) {
  int i = blockIdx.x * 256 + threadIdx.x;
  if (i >= NB * 786432) return;
  int nl = i / 786432;
  int rem = i - nl * 786432;
  int sample = n0 + nl;
  float v;
  if (sid == 0) {
    v = igt[sample * 786432 + rem];
  } else if (sid == 1) {
    v = iout[sample * 786432 + rem];
  } else {
    int pix = rem & 262143;
    float mk = mask[sample * 262144 + pix];
    v = (mk != 0.0f) ? igt[sample * 786432 + rem] : iout[sample * 786432 + rem];
  }
  x0[i] = v;
}

// Pack fp32 OIHW weights -> bf16 [tap][cout][cin].
__global__ __launch_bounds__(256) void pack_w(const float* __restrict__ w,
                                              __hip_bfloat16* __restrict__ wp,
                                              int Cin, int Cout) {
  int i = blockIdx.x * 256 + threadIdx.x;
  if (i >= Cout * Cin * 9) return;
  int o = i % 9;
  int rem = i / 9;
  int ci = rem % Cin;
  int co = rem / Cin;
  wp[((long)(o * Cout + co)) * Cin + ci] = __float2bfloat16(w[i]);
}

// conv1: 3->64 fp32 direct, bias+relu, bf16 NHWC out. (r4-proven)
__global__ __launch_bounds__(256) void conv1_k(
    const float* __restrict__ in, const float* __restrict__ wgt,
    const float* __restrict__ bias, __hip_bfloat16* __restrict__ out,
    int H, int W) {
  constexpr int TCO = 16;
  constexpr int Cin = 3;
  __shared__ float s_in[Cin][34][34];
  __shared__ float s_w[Cin][9][TCO];
  const int tid = threadIdx.x;
  const int tx = tid & 31;
  const int tyq = tid >> 5;
  const int bx = blockIdx.x, by = blockIdx.y;
  const int n = blockIdx.z >> 2;
  const int co0 = (blockIdx.z & 3) * TCO;
  const int x0g = bx * 32 - 1;
  const int y0g = by * 32 - 1;

  float acc[4][TCO];
#pragma unroll
  for (int p = 0; p < 4; ++p)
#pragma unroll
    for (int t = 0; t < TCO; ++t) acc[p][t] = 0.0f;

  for (int e = tid; e < Cin * 1156; e += 256) {
    int ci = e / 1156;
    int rem = e - ci * 1156;
    int r = rem / 34;
    int c = rem - r * 34;
    int gy = y0g + r, gx = x0g + c;
    float v = 0.0f;
    if (gy >= 0 && gy < H && gx >= 0 && gx < W)
      v = in[((long)(n * Cin + ci) * H + gy) * W + gx];
    s_in[ci][r][c] = v;
  }
  for (int e = tid; e < Cin * 9 * TCO; e += 256) {
    int ci = e / (9 * TCO);
    int rem = e - ci * 9 * TCO;
    int k = rem / TCO;
    int t = rem - k * TCO;
    s_w[ci][k][t] = wgt[((co0 + t) * Cin + ci) * 9 + k];
  }
  __syncthreads();

  for (int ci = 0; ci < Cin; ++ci) {
    float iv[6][3];
#pragma unroll
    for (int dr = 0; dr < 6; ++dr)
#pragma unroll
      for (int dc = 0; dc < 3; ++dc)
        iv[dr][dc] = s_in[ci][tyq * 4 + dr][tx + dc];
#pragma unroll
    for (int ky = 0; ky < 3; ++ky)
#pragma unroll
      for (int kx = 0; kx < 3; ++kx) {
        const int kk = ky * 3 + kx;
        const float4 w0 = *(const float4*)&s_w[ci][kk][0];
        const float4 w1 = *(const float4*)&s_w[ci][kk][4];
        const float4 w2 = *(const float4*)&s_w[ci][kk][8];
        const float4 w3 = *(const float4*)&s_w[ci][kk][12];
        const float wv[16] = {w0.x, w0.y, w0.z, w0.w, w1.x, w1.y, w1.z, w1.w,
                              w2.x, w2.y, w2.z, w2.w, w3.x, w3.y, w3.z, w3.w};
#pragma unroll
        for (int p = 0; p < 4; ++p) {
          const float v = iv[p + ky][kx];
#pragma unroll
          for (int t = 0; t < TCO; ++t) acc[p][t] += v * wv[t];
        }
      }
  }

  float bv[TCO];
#pragma unroll
  for (int t = 0; t < TCO; ++t) bv[t] = bias[co0 + t];
  const int xg = bx * 32 + tx;
#pragma unroll
  for (int p = 0; p < 4; ++p) {
    int yg = by * 32 + tyq * 4 + p;
#pragma unroll
    for (int t = 0; t < TCO; ++t) {
      float v = fmaxf(acc[p][t] + bv[t], 0.0f);
      out[(((long)n * H + yg) * W + xg) * 64 + co0 + t] = __float2bfloat16(v);
    }
  }
}

// ---------------------------------------------------------------------------
// conv_v3: MFMA 3x3 conv, bias+relu, bf16 NHWC. B-weights from global.
// Block: 256 thr = 4 waves; wave = 1 row x 128 px x 64 co (m8 x n4).
// LDS: A-tile only, 6x130x32ch = 49,920 B -> 3 blocks/CU.
// Grid: (W/128, H/4, n_imgs * Cout/64).
// ---------------------------------------------------------------------------
__global__ __launch_bounds__(256, 2) void conv_v3(
    const __hip_bfloat16* __restrict__ act,
    const __hip_bfloat16* __restrict__ wp, const float* __restrict__ bias,
    __hip_bfloat16* __restrict__ out, int Cin, int Cout, int H, int W) {
  __shared__ __align__(16) short ApS[6 * 130 * 32];
  const int tid = threadIdx.x;
  const int lane = tid & 63;
  const int wv = tid >> 6;  // row within block
  const int quad = lane >> 4, l15 = lane & 15;
  const int coB = Cout >> 6;
  const int n = blockIdx.z / coB;
  const int co0 = (blockIdx.z % coB) << 6;
  const int x0 = blockIdx.x << 7;
  const int y0 = blockIdx.y << 2;

  f32x4_t acc[8][4];
#pragma unroll
  for (int mt = 0; mt < 8; ++mt)
#pragma unroll
    for (int nt = 0; nt < 4; ++nt) acc[mt][nt] = (f32x4_t)0.0f;

  for (int cb = 0; cb < Cin; cb += 32) {
    for (int e = tid; e < 3120; e += 256) {  // 6*130*4 16B-entries
      int q = e & 3, pos = e >> 2;
      int r = pos / 130, c = pos - r * 130;
      int gy = y0 - 1 + r, gx = x0 - 1 + c;
      uint4 v = make_uint4(0, 0, 0, 0);
      if (gy >= 0 && gy < H && gx >= 0 && gx < W)
        v = *(const uint4*)(act + (((long)n * H + gy) * W + gx) * Cin + cb +
                            q * 8);
      *(uint4*)&ApS[pos * 32 + q * 8] = v;
    }
    __syncthreads();

#pragma unroll
    for (int o = 0; o < 9; ++o) {
      const int dy = o / 3, dx = o % 3;
      const __hip_bfloat16* wB =
          wp + ((long)(o * Cout + co0)) * Cin + cb + quad * 8;
      bf16x8_t bf[4];
#pragma unroll
      for (int nt = 0; nt < 4; ++nt)
        bf[nt] = *(const bf16x8_t*)(wB + (long)(nt * 16 + l15) * Cin);
#pragma unroll
      for (int mt = 0; mt < 8; ++mt) {
        const bf16x8_t a = *(const bf16x8_t*)&ApS
            [((wv + dy) * 130 + mt * 16 + l15 + dx) * 32 + quad * 8];
#pragma unroll
        for (int nt = 0; nt < 4; ++nt)
          acc[mt][nt] = __builtin_amdgcn_mfma_f32_16x16x32_bf16(
              a, bf[nt], acc[mt][nt], 0, 0, 0);
      }
    }
    __syncthreads();
  }

  float bv[4];
#pragma unroll
  for (int nt = 0; nt < 4; ++nt) bv[nt] = bias[co0 + nt * 16 + l15];
  const int y = y0 + wv;
#pragma unroll
  for (int mt = 0; mt < 8; ++mt)
#pragma unroll
    for (int nt = 0; nt < 4; ++nt) {
      const int col = co0 + nt * 16 + l15;
#pragma unroll
      for (int reg = 0; reg < 4; ++reg) {
        int px = mt * 16 + quad * 4 + reg;
        float v = fmaxf(acc[mt][nt][reg] + bv[nt], 0.0f);
        out[(((long)n * H + y) * W + x0 + px) * Cout + col] =
            __float2bfloat16(v);
      }
    }
}

// ---------------------------------------------------------------------------
// conv_v3p: conv_v3 + fused 2x2 maxpool (in-register). Wave = 2 rows x 64 px
// x 64 co: m-tiles 0..3 = row0, 4..7 = row1. Pool pairs: x-pairs are acc reg
// pairs (0,1)/(2,3) (C row = quad*4+reg = pixel); row pair = mt vs mt+4.
// Output: pooled bf16 NHWC [n][H/2][W/2][Cout].
// LDS: 10x66x32ch = 42,240 B -> 3 blocks/CU. Grid: (W/64, H/8, n*Cout/64).
// ---------------------------------------------------------------------------
__global__ __launch_bounds__(256, 2) void conv_v3p(
    const __hip_bfloat16* __restrict__ act,
    const __hip_bfloat16* __restrict__ wp, const float* __restrict__ bias,
    __hip_bfloat16* __restrict__ out, int Cin, int Cout, int H, int W) {
  __shared__ __align__(16) short ApS[10 * 66 * 32];
  const int tid = threadIdx.x;
  const int lane = tid & 63;
  const int wv = tid >> 6;  // row-pair within block
  const int quad = lane >> 4, l15 = lane & 15;
  const int coB = Cout >> 6;
  const int n = blockIdx.z / coB;
  const int co0 = (blockIdx.z % coB) << 6;
  const int x0g = blockIdx.x << 6;
  const int y0 = blockIdx.y << 3;

  f32x4_t acc[8][4];
#pragma unroll
  for (int mt = 0; mt < 8; ++mt)
#pragma unroll
    for (int nt = 0; nt < 4; ++nt) acc[mt][nt] = (f32x4_t)0.0f;

  for (int cb = 0; cb < Cin; cb += 32) {
    for (int e = tid; e < 2640; e += 256) {  // 10*66*4
      int q = e & 3, pos = e >> 2;
      int r = pos / 66, c = pos - r * 66;
      int gy = y0 - 1 + r, gx = x0g - 1 + c;
      uint4 v = make_uint4(0, 0, 0, 0);
      if (gy >= 0 && gy < H && gx >= 0 && gx < W)
        v = *(const uint4*)(act + (((long)n * H + gy) * W + gx) * Cin + cb +
                            q * 8);
      *(uint4*)&ApS[pos * 32 + q * 8] = v;
    }
    __syncthreads();

#pragma unroll
    for (int o = 0; o < 9; ++o) {
      const int dy = o / 3, dx = o % 3;
      const __hip_bfloat16* wB =
          wp + ((long)(o * Cout + co0)) * Cin + cb + quad * 8;
      bf16x8_t bf[4];
#pragma unroll
      for (int nt = 0; nt < 4; ++nt)
        bf[nt] = *(const bf16x8_t*)(wB + (long)(nt * 16 + l15) * Cin);
#pragma unroll
      for (int mt = 0; mt < 8; ++mt) {
        const int rl = 2 * wv + (mt >> 2) + dy;       // 0..9
        const int pl = (mt & 3) * 16 + l15 + dx;      // 0..65
        const bf16x8_t a = *(const bf16x8_t*)&ApS[(rl * 66 + pl) * 32 +
                                                  quad * 8];
#pragma unroll
        for (int nt = 0; nt < 4; ++nt)
          acc[mt][nt] = __builtin_amdgcn_mfma_f32_16x16x32_bf16(
              a, bf[nt], acc[mt][nt], 0, 0, 0);
      }
    }
    __syncthreads();
  }

  const int Ho = H >> 1, Wo = W >> 1;
  const int ho = (blockIdx.y << 2) + wv;
  float bv[4];
#pragma unroll
  for (int nt = 0; nt < 4; ++nt) bv[nt] = bias[co0 + nt * 16 + l15];
#pragma unroll
  for (int mtA = 0; mtA < 4; ++mtA)
#pragma unroll
    for (int nt = 0; nt < 4; ++nt) {
      const int col = co0 + nt * 16 + l15;
#pragma unroll
      for (int half = 0; half < 2; ++half) {
        float m0 = fmaxf(
            fmaxf(acc[mtA][nt][2 * half], acc[mtA][nt][2 * half + 1]),
            fmaxf(acc[mtA + 4][nt][2 * half], acc[mtA + 4][nt][2 * half + 1]));
        float v = fmaxf(m0 + bv[nt], 0.0f);
        int wo = (blockIdx.x << 5) + mtA * 8 + quad * 2 + half;
        out[(((long)n * Ho + ho) * Wo + wo) * Cout + col] = __float2bfloat16(v);
      }
    }
}

// 2x2 maxpool: bf16 NHWC in -> bf16 NHWC out + bf16 col-major planar
// out_pT[plane][x][y]. (r5-proven; L1 level only.)
__global__ __launch_bounds__(256) void pool_k(
    const __hip_bfloat16* __restrict__ in, __hip_bfloat16* __restrict__ out_n,
    __hip_bfloat16* __restrict__ out_pT, int C, int H, int W) {
  const int Ho = H >> 1, Wo = W >> 1;
  const int cl = threadIdx.x & 31;
  const int wl = threadIdx.x >> 5;
  const int cg = C >> 5;
  const int nl = blockIdx.z / cg;
  const int c = (blockIdx.z % cg) * 32 + cl;
  const int wo = blockIdx.x * 8 + wl;
  const int ho0 = blockIdx.y * 8;
  __align__(16) __hip_bfloat16 res[8];
#pragma unroll
  for (int i = 0; i < 8; ++i) {
    int ho = ho0 + i;
    long base = (((long)nl * H + 2 * ho) * W + 2 * wo) * C + c;
    float a = b2f(in[base]);
    float b = b2f(in[base + C]);
    float d = b2f(in[base + (long)W * C]);
    float e = b2f(in[base + (long)W * C + C]);
    float m = fmaxf(fmaxf(a, b), fmaxf(d, e));
    __hip_bfloat16 r = __float2bfloat16(m);
    res[i] = r;
    out_n[(((long)nl * Ho + ho) * Wo + wo) * C + c] = r;
  }
  *(uint4*)&out_pT[((long)(nl * C + c) * Wo + wo) * Ho + ho0] =
      *(const uint4*)res;
}

// NHWC [j][Ho][Wo][C] -> col-major planar [(j*C+c)][Wo][Ho].
// Block 256 = 32c x 8wo, 8 ho per thread. Grid (Wo/8, Ho/8, nimg*C/32).
__global__ __launch_bounds__(256) void transpose_k(
    const __hip_bfloat16* __restrict__ in, __hip_bfloat16* __restrict__ out,
    int C, int Ho, int Wo) {
  const int cl = threadIdx.x & 31;
  const int wl = threadIdx.x >> 5;
  const int cg = C >> 5;
  const int j = blockIdx.z / cg;
  const int c = (blockIdx.z % cg) * 32 + cl;
  const int wo = blockIdx.x * 8 + wl;
  const int ho0 = blockIdx.y * 8;
  __align__(16) __hip_bfloat16 res[8];
#pragma unroll
  for (int i = 0; i < 8; ++i)
    res[i] = in[(((long)j * Ho + ho0 + i) * Wo + wo) * C + c];
  *(uint4*)&out[((long)(j * C + c) * Wo + wo) * Ho + ho0] =
      *(const uint4*)res;
}

// l_perc partial: sum |cur - gt| over 8*M8 bf16 elements -> slots[2]
__global__ __launch_bounds__(256) void perc_kernel(
    const __hip_bfloat16* __restrict__ gt, const __hip_bfloat16* __restrict__ cur,
    int M8, float* __restrict__ slots) {
  __shared__ float s4[4];
  const uint4* g4 = (const uint4*)gt;
  const uint4* c4 = (const uint4*)cur;
  float acc = 0.0f;
  for (int i = blockIdx.x * 256 + threadIdx.x; i < M8; i += gridDim.x * 256) {
    uint4 g = g4[i], c = c4[i];
    const unsigned* gu = (const unsigned*)&g;
    const unsigned* cu = (const unsigned*)&c;
#pragma unroll
    for (int k = 0; k < 4; ++k) {
      float g0 = __uint_as_float(gu[k] << 16);
      float g1 = __uint_as_float(gu[k] & 0xffff0000u);
      float c0 = __uint_as_float(cu[k] << 16);
      float c1 = __uint_as_float(cu[k] & 0xffff0000u);
      acc += fabsf(c0 - g0) + fabsf(c1 - g1);
    }
  }
  float r = blk_sum256(acc, s4);
  if (threadIdx.x == 0) atomicAdd(&slots[2], r);
}

// Style partial via bf16 MFMA (r5-proven). Inputs col-major planar bf16.
template <int BM>
__global__ __launch_bounds__(256) void gram_mfma(
    const __hip_bfloat16* __restrict__ gt_p,
    const __hip_bfloat16* __restrict__ cur_p, int Wp, int Hp, float fscale,
    float* __restrict__ slots) {
  constexpr int COLS = BM + 64;
  constexpr int WR = BM / 4;
  constexpr int MT = WR / 16;
  __shared__ __align__(16) short S[2 * COLS * 40];
  __shared__ float s4[4];
  const int tid = threadIdx.x;
  const int lane = tid & 63;
  const int wvi = tid >> 6;
  const int quad = lane >> 4, l15 = lane & 15;
  const int vt = blockIdx.x * 64;
  const int wt = blockIdx.y * BM;
  const long plane = (long)blockIdx.z * Wp * Hp;
  const __hip_bfloat16* bases[2] = {gt_p + plane, cur_p + plane};

  f32x4_t acc[2][MT][4];
#pragma unroll
  for (int t = 0; t < 2; ++t)
#pragma unroll
    for (int mt = 0; mt < MT; ++mt)
#pragma unroll
      for (int nt = 0; nt < 4; ++nt) acc[t][mt][nt] = (f32x4_t)0.0f;

  const int nchunk = 2 * COLS * 4;
  for (int h0 = 0; h0 < Hp; h0 += 32) {
    for (int e = tid; e < nchunk; e += 256) {
      int chunk = e & 3;
      int colt = e >> 2;
      int t = colt / COLS;
      int col = colt - t * COLS;
      int sc = (col < BM) ? (wt + col) : (vt + col - BM);
      uint4 v = *(const uint4*)(bases[t] + (long)sc * Hp + h0 + chunk * 8);
      *(uint4*)&S[(t * COLS + col) * 40 + chunk * 8] = v;
    }
    __syncthreads();
#pragma unroll
    for (int t = 0; t < 2; ++t) {
      bf16x8_t bf[4];
#pragma unroll
      for (int nt = 0; nt < 4; ++nt)
        bf[nt] = *(const bf16x8_t*)&S[(t * COLS + BM + nt * 16 + l15) * 40 +
                                      quad * 8];
#pragma unroll
      for (int mt = 0; mt < MT; ++mt) {
        bf16x8_t a = *(const bf16x8_t*)&S[(t * COLS + wvi * WR + mt * 16 + l15) *
                                              40 + quad * 8];
#pragma unroll
        for (int nt = 0; nt < 4; ++nt)
          acc[t][mt][nt] = __builtin_amdgcn_mfma_f32_16x16x32_bf16(
              a, bf[nt], acc[t][mt][nt], 0, 0, 0);
      }
    }
    __syncthreads();
  }

  float local = 0.0f;
#pragma unroll
  for (int mt = 0; mt < MT; ++mt)
#pragma unroll
    for (int nt = 0; nt < 4; ++nt)
#pragma unroll
      for (int reg = 0; reg < 4; ++reg)
        local += fabsf(acc[1][mt][nt][reg] - acc[0][mt][nt][reg]);
  float r = blk_sum256(local, s4);
  if (tid == 0) atomicAdd(&slots[3], r * fscale);
}

__global__ void combine_kernel(const float* __restrict__ slots,
                               float* __restrict__ out) {
  if (threadIdx.x == 0) {
    const float Nn = 1572864.0f;
    const float Nigt = 8388608.0f;
    out[0] = 2.0f * slots[0] / Nn + slots[1] / Nn + slots[2] / Nigt + slots[3];
  }
}

extern "C" void kernel_launch(void* const* d_in, const int* in_sizes, int n_in,
                              void* d_out, int out_size, void* d_ws,
                              size_t ws_size, hipStream_t stream) {
  (void)in_sizes; (void)n_in; (void)out_size;
  const float* igt = (const float*)d_in[0];
  const float* iout = (const float*)d_in[1];
  const float* mask = (const float*)d_in[2];
  const float* w[7];
  const float* b[7];
  for (int i = 0; i < 7; ++i) {
    w[i] = (const float*)d_in[3 + 2 * i];
    b[i] = (const float*)d_in[4 + 2 * i];
  }
  float* slots = (float*)d_ws;

  __hip_bfloat16* wpk = (__hip_bfloat16*)((char*)d_ws + 256);
  const long wpOff[6] = {0, 36864, 110592, 258048, 552960, 1142784};
  const int wpCin[6] = {64, 64, 128, 128, 256, 256};
  const int wpCout[6] = {64, 128, 128, 256, 256, 256};
  // weights end at byte 3,465,472

  // NB=2 tier needs 211,083,520 B; NB=1 needs 107,274,496 B (< proven 116.4MB)
  const size_t NEED2 = 211083520ULL;
  const int NB = (ws_size >= NEED2) ? 2 : 1;
  const int B3 = 3 * NB;

  char* base = (char*)d_ws + 3465472;
  __hip_bfloat16* bufA = (__hip_bfloat16*)base;                       // NB*33.55MB
  __hip_bfloat16* bufB = (__hip_bfloat16*)(base + (size_t)NB * 33554432);
  float* x0 = (float*)(base + (size_t)NB * 67108864);                 // NB*3.15MB
  __hip_bfloat16* P1N = (__hip_bfloat16*)(base + (size_t)NB * 70254592);  // 3NB imgs NHWC
  __hip_bfloat16* pgT1 = (__hip_bfloat16*)(base + (size_t)NB * 95420416); // NB planar
  __hip_bfloat16* pcT1 = bufA + (size_t)NB * 12582912;  // bufA tail (dead zone)
  // Batched-phase aliases (all live ranges verified sequential):
  __hip_bfloat16* T = bufA;                              // conv3 out, NB*50.33MB
  __hip_bfloat16* P2N = P1N;                             // pooled L2 NHWC
  __hip_bfloat16* P2T = P1N + (size_t)NB * 6291456;      // planar L2
  __hip_bfloat16* Y5 = bufA;                             // NB*25.17MB
  __hip_bfloat16* Y6 = bufA + (size_t)NB * 12582912;     // NB*25.17MB
  __hip_bfloat16* P3N = bufA + (size_t)NB * 25165824;    // pooled L3 NHWC
  __hip_bfloat16* P3T = pgT1;                            // planar L3

  const float fs1 = (float)(1.0 / (4194304.0 * 4096.0));
  const float fs2 = (float)(1.0 / (2097152.0 * 16384.0));
  const float fs3 = (float)(1.0 / (1048576.0 * 65536.0));

  init_slots<<<1, 64, 0, stream>>>(slots);
  l1_kernel<<<304, 256, 0, stream>>>(igt, iout, mask, slots);
  for (int l = 0; l < 6; ++l) {
    int elems = wpCout[l] * wpCin[l] * 9;
    pack_w<<<(elems + 255) / 256, 256, 0, stream>>>(w[l + 1], wpk + wpOff[l],
                                                    wpCin[l], wpCout[l]);
  }

  for (int n0 = 0; n0 < 2; n0 += NB) {
    // ---- per-stream: conv1, conv2, pool1, perc1/gram1 ----
    for (int s = 0; s < 3; ++s) {
      pack_kernel<<<NB * 3072, 256, 0, stream>>>(igt, iout, mask, x0, s, n0, NB);
      conv1_k<<<dim3(16, 16, NB * 4), 256, 0, stream>>>(x0, w[0], b[0], bufA, 512, 512);
      conv_v3<<<dim3(4, 128, NB), 256, 0, stream>>>(
          bufA, wpk + wpOff[0], b[1], bufB, 64, 64, 512, 512);
      pool_k<<<dim3(32, 32, NB * 2), 256, 0, stream>>>(
          bufB, P1N + (size_t)s * NB * 4194304, (s ? pcT1 : pgT1), 64, 512, 512);
      if (s > 0) {
        perc_kernel<<<304, 256, 0, stream>>>(pgT1, pcT1, NB * 524288, slots);
        gram_mfma<128><<<dim3(4, 2, NB * 64), 256, 0, stream>>>(
            pgT1, pcT1, 256, 256, fs1, slots);
      }
    }
    // ---- batched over 3NB images: conv3..conv7, pools, perc/gram L2/L3 ----
    conv_v3<<<dim3(2, 64, B3 * 2), 256, 0, stream>>>(
        P1N, wpk + wpOff[1], b[2], T, 64, 128, 256, 256);
    conv_v3p<<<dim3(4, 32, B3 * 2), 256, 0, stream>>>(
        T, wpk + wpOff[2], b[3], P2N, 128, 128, 256, 256);
    transpose_k<<<dim3(16, 16, B3 * 4), 256, 0, stream>>>(P2N, P2T, 128, 128, 128);
    for (int s = 1; s <= 2; ++s) {
      perc_kernel<<<304, 256, 0, stream>>>(
          P2T, P2T + (size_t)s * NB * 2097152, NB * 262144, slots);
      gram_mfma<128><<<dim3(2, 1, NB * 128), 256, 0, stream>>>(
          P2T, P2T + (size_t)s * NB * 2097152, 128, 128, fs2, slots);
    }
    conv_v3<<<dim3(1, 32, B3 * 4), 256, 0, stream>>>(
        P2N, wpk + wpOff[3], b[4], Y5, 128, 256, 128, 128);
    conv_v3<<<dim3(1, 32, B3 * 4), 256, 0, stream>>>(
        Y5, wpk + wpOff[4], b[5], Y6, 256, 256, 128, 128);
    conv_v3p<<<dim3(2, 16, B3 * 4), 256, 0, stream>>>(
        Y6, wpk + wpOff[5], b[6], P3N, 256, 256, 128, 128);
    transpose_k<<<dim3(8, 8, B3 * 8), 256, 0, stream>>>(P3N, P3T, 256, 64, 64);
    for (int s = 1; s <= 2; ++s) {
      perc_kernel<<<304, 256, 0, stream>>>(
          P3T, P3T + (size_t)s * NB * 1048576, NB * 131072, slots);
      gram_mfma<64><<<dim3(1, 1, NB * 256), 256, 0, stream>>>(
          P3T, P3T + (size_t)s * NB * 1048576, 64, 64, fs3, slots);
    }
  }

  combine_kernel<<<1, 64, 0, stream>>>(slots, (float*)d_out);
}